// Round 14
// baseline (229.922 us; speedup 1.0000x reference)
//
#include <hip/hip_runtime.h>
#include <math.h>

#define NN 32768      // nodes per side
#define BB 64         // graphs per side
#define NPG 512
#define DD 128
#define LL 3
#define EE 524288     // edges per side
#define NBINS 16
#define KNTN 16
#define NND (NN*DD)
#define NBKT 128      // CSR buckets (512 nodes each)
#define BSEG 56       // per-(block,bucket) ibuf segment (mean 16)
#define BCAPE 10240   // esrc capacity per bucket (mean 8192, std ~90)
#define SCAP 3072     // staged-index cap for 128 nodes (mean 2176, std ~47)

typedef unsigned short ushort_t;
typedef __attribute__((ext_vector_type(8))) short short8;
typedef __attribute__((ext_vector_type(4))) float f32x4;

__device__ __forceinline__ ushort_t f2bf(float f) {
    unsigned u = __builtin_bit_cast(unsigned, f);
    u += 0x7FFFu + ((u >> 16) & 1u);
    return (ushort_t)(u >> 16);
}
__device__ __forceinline__ float bf2f(ushort_t h) {
    unsigned u = ((unsigned)h) << 16;
    return __builtin_bit_cast(float, u);
}
__device__ __forceinline__ unsigned pack2(float a, float b) {
    return (unsigned)f2bf(a) | ((unsigned)f2bf(b) << 16);
}
__device__ __forceinline__ float lo16(unsigned u) { return __builtin_bit_cast(float, u << 16); }
__device__ __forceinline__ float hi16(unsigned u) { return __builtin_bit_cast(float, u & 0xffff0000u); }

// ---------- CSR pass A + prep fused ----------
__global__ __launch_bounds__(256) void k_bucket(const int* __restrict__ ei1,
                                                const int* __restrict__ ei2,
                                                unsigned* __restrict__ ibuf,
                                                int* __restrict__ bcnt,
                                                const float* __restrict__ gw,
                                                const float* __restrict__ cw,
                                                ushort_t* __restrict__ wbf,
                                                const float* __restrict__ gcn_b,
                                                const float* __restrict__ bn_g,
                                                const float* __restrict__ bn_b,
                                                const float* __restrict__ bn_m,
                                                const float* __restrict__ bn_v,
                                                float* __restrict__ bnsc,
                                                float* __restrict__ bnsh) {
    int t = threadIdx.x;
    int blk = blockIdx.x;
    if (blk >= 512) {
        if (blk < 576) {
            int i = (blk - 512) * 256 + t;
            const float4 v = (i < 3 * DD * DD / 4) ? ((const float4*)gw)[i]
                                                   : ((const float4*)cw)[i - 3 * DD * DD / 4];
            uint2 o;
            o.x = pack2(v.x, v.y);
            o.y = pack2(v.z, v.w);
            ((uint2*)wbf)[i] = o;
        } else if (t < DD) {
            #pragma unroll
            for (int l = 0; l < LL; l++) {
                int c = l * DD + t;
                float sc = bn_g[c] * rsqrtf(bn_v[c] + 1e-5f);
                bnsc[c] = sc;
                bnsh[c] = (gcn_b[c] - bn_m[c]) * sc + bn_b[c];
            }
        }
        return;
    }
    __shared__ int cnt[NBKT];
    const int* ei = (blk < 256) ? ei1 : ei2;
    int ebase = (blk & 255) * 2048;
    int addn = (blk < 256) ? 0 : NN;
    for (int i = t; i < NBKT; i += 256) cnt[i] = 0;
    __syncthreads();
    #pragma unroll
    for (int k = 0; k < 8; k++) {
        int e = ebase + t + k * 256;
        int s = ei[e] + addn;
        int d = ei[EE + e] + addn;
        unsigned p = (unsigned)s | ((unsigned)d << 16);
        int bk = (unsigned)d >> 9;
        int rk = atomicAdd(&cnt[bk], 1);
        ibuf[(size_t)(bk * 512 + blk) * BSEG + rk] = p;
    }
    __syncthreads();
    if (t < NBKT) bcnt[t * 512 + blk] = cnt[t];
}

// ---------- CSR pass B ----------
__global__ __launch_bounds__(256) void k_bcsr(const unsigned* __restrict__ ibuf,
                                              const int* __restrict__ bcnt,
                                              int* __restrict__ deg,
                                              float* __restrict__ dinv,
                                              int* __restrict__ rowstart,
                                              ushort_t* __restrict__ esrc) {
    __shared__ int cnt[512];
    __shared__ int ps[256];
    __shared__ int lcur[512];
    int bk = blockIdx.x, t = threadIdx.x;
    for (int i = t; i < 512; i += 256) cnt[i] = 0;
    __syncthreads();
    for (int b = t; b < 512; b += 256) {
        int n = bcnt[bk * 512 + b];
        const unsigned* seg = ibuf + (size_t)(bk * 512 + b) * BSEG;
        for (int i = 0; i < n; i++) {
            int dl = (seg[i] >> 16) & 511;
            atomicAdd(&cnt[dl], 1);
        }
    }
    __syncthreads();
    int c0 = cnt[2 * t], c1 = cnt[2 * t + 1];
    ps[t] = c0 + c1;
    __syncthreads();
    for (int o = 1; o < 256; o <<= 1) {
        int v = (t >= o) ? ps[t - o] : 0;
        __syncthreads();
        ps[t] += v;
        __syncthreads();
    }
    int excl = (t == 0) ? 0 : ps[t - 1];
    int base = bk * BCAPE;
    int g0 = bk * 512 + 2 * t, g1 = g0 + 1;
    deg[g0] = c0; deg[g1] = c1;
    dinv[g0] = rsqrtf((float)c0 + 1.0f);
    dinv[g1] = rsqrtf((float)c1 + 1.0f);
    int r0 = base + excl, r1 = base + excl + c0;
    rowstart[g0] = r0;
    rowstart[g1] = r1;
    lcur[2 * t] = r0;
    lcur[2 * t + 1] = r1;
    __syncthreads();
    for (int b = t; b < 512; b += 256) {
        int n = bcnt[bk * 512 + b];
        const unsigned* seg = ibuf + (size_t)(bk * 512 + b) * BSEG;
        for (int i = 0; i < n; i++) {
            unsigned p = seg[i];
            int dl = (p >> 16) & 511;
            int slot = atomicAdd(&lcur[dl], 1);
            esrc[slot] = (ushort_t)(p & 0xffffu);
        }
    }
}

// ---------- MFMA GEMM: W staged in LDS (swizzled), 128 rows/block ----------
// XF=1: A-operand read from fp32 x1/x2.  EPI 0: bf16 out * dscale.
// EPI 2: bias+tanh+attention-score -> Sout.
template<int EPI, int XF>
__global__ __launch_bounds__(256) void k_mgemm(const ushort_t* __restrict__ X,
                                               const float* __restrict__ Xf1,
                                               const float* __restrict__ Xf2,
                                               const ushort_t* __restrict__ Wb,
                                               const float* __restrict__ bias,
                                               ushort_t* __restrict__ Out,
                                               const float* __restrict__ aw,
                                               const float* __restrict__ ab,
                                               float* __restrict__ Sout,
                                               const float* __restrict__ dscale) {
    __shared__ __align__(16) ushort_t wlds[128 * 128];
    int t = threadIdx.x;
    {
        int r = t >> 1, h = t & 1;
        const uint4* src = (const uint4*)(Wb + (size_t)r * DD + h * 64);
        #pragma unroll
        for (int i = 0; i < 8; i++) {
            int co = h * 128 + i * 16;
            int sw = co ^ ((r & 7) << 4);
            *(uint4*)&wlds[r * DD + (sw >> 1)] = src[i];
        }
    }
    __syncthreads();
    int w = t >> 6, l = t & 63;
    int rw = blockIdx.x * 128 + w * 32;
    int lr = l & 15, lg = l >> 4;
    f32x4 acc[2][8];
    #pragma unroll
    for (int g = 0; g < 2; g++)
        #pragma unroll
        for (int c = 0; c < 8; c++) acc[g][c] = (f32x4){0.f, 0.f, 0.f, 0.f};
    const ushort_t* xrow0 = X + (size_t)(rw + lr) * DD + lg * 8;
    const ushort_t* xrow1 = xrow0 + (size_t)16 * DD;
    const float* xf0 = nullptr;
    if (XF) {
        const float* xb = (rw < NN) ? Xf1 : (Xf2 - (size_t)NN * DD);
        xf0 = xb + (size_t)(rw + lr) * DD + lg * 8;
    }
    int swl = (lr & 7) << 4;
    for (int kt = 0; kt < 4; kt++) {
        short8 a0, a1;
        if (XF) {
            float4 va = *(const float4*)(xf0 + kt * 32);
            float4 vb = *(const float4*)(xf0 + kt * 32 + 4);
            float4 vc = *(const float4*)(xf0 + (size_t)16 * DD + kt * 32);
            float4 vd = *(const float4*)(xf0 + (size_t)16 * DD + kt * 32 + 4);
            a0[0] = (short)f2bf(va.x); a0[1] = (short)f2bf(va.y);
            a0[2] = (short)f2bf(va.z); a0[3] = (short)f2bf(va.w);
            a0[4] = (short)f2bf(vb.x); a0[5] = (short)f2bf(vb.y);
            a0[6] = (short)f2bf(vb.z); a0[7] = (short)f2bf(vb.w);
            a1[0] = (short)f2bf(vc.x); a1[1] = (short)f2bf(vc.y);
            a1[2] = (short)f2bf(vc.z); a1[3] = (short)f2bf(vc.w);
            a1[4] = (short)f2bf(vd.x); a1[5] = (short)f2bf(vd.y);
            a1[6] = (short)f2bf(vd.z); a1[7] = (short)f2bf(vd.w);
        } else {
            a0 = *(const short8*)(xrow0 + kt * 32);
            a1 = *(const short8*)(xrow1 + kt * 32);
        }
        int colsw = (kt * 64 + lg * 16) ^ swl;
        #pragma unroll
        for (int c = 0; c < 8; c++) {
            int row = c * 16 + lr;
            short8 b = *(const short8*)&wlds[row * DD + (colsw >> 1)];
            acc[0][c] = __builtin_amdgcn_mfma_f32_16x16x32_bf16(a0, b, acc[0][c], 0, 0, 0);
            acc[1][c] = __builtin_amdgcn_mfma_f32_16x16x32_bf16(a1, b, acc[1][c], 0, 0, 0);
        }
    }
    if (EPI == 0) {
        float ds[2][4];
        #pragma unroll
        for (int g = 0; g < 2; g++)
            #pragma unroll
            for (int q = 0; q < 4; q++) ds[g][q] = dscale[rw + g * 16 + lg * 4 + q];
        #pragma unroll
        for (int g = 0; g < 2; g++)
            #pragma unroll
            for (int c = 0; c < 8; c++) {
                int col = c * 16 + lr;
                #pragma unroll
                for (int q = 0; q < 4; q++)
                    Out[(size_t)(rw + g * 16 + lg * 4 + q) * DD + col] = f2bf(acc[g][c][q] * ds[g][q]);
            }
    } else {
        float rs[2][4] = {};
        #pragma unroll
        for (int c = 0; c < 8; c++) {
            int col = c * 16 + lr;
            float bv = bias[col], wv = aw[col];
            #pragma unroll
            for (int g = 0; g < 2; g++)
                #pragma unroll
                for (int q = 0; q < 4; q++)
                    rs[g][q] += tanhf(acc[g][c][q] + bv) * wv;
        }
        #pragma unroll
        for (int m = 1; m < 16; m <<= 1)
            #pragma unroll
            for (int g = 0; g < 2; g++)
                #pragma unroll
                for (int q = 0; q < 4; q++) rs[g][q] += __shfl_xor(rs[g][q], m);
        if (lr == 0) {
            float a0 = ab[0];
            #pragma unroll
            for (int g = 0; g < 2; g++)
                #pragma unroll
                for (int q = 0; q < 4; q++)
                    Sout[rw + g * 16 + lg * 4 + q] = rs[g][q] + a0;
        }
    }
}

#define GATHER(u, s) uint4 u = Hu4[(size_t)(s) * 16 + cl]
#define ACCUM(u) \
    a0 += lo16(u.x); a1 += hi16(u.x); a2 += lo16(u.y); a3 += hi16(u.y); \
    a4 += lo16(u.z); a5 += hi16(u.z); a6 += lo16(u.w); a7 += hi16(u.w)

// ---------- layer-0 aggregate: gathers Hs, outputs PRE-SCALED As = dinv * relu(BN(...)) ----------
__global__ __launch_bounds__(256) void k_agg0(
    const ushort_t* __restrict__ Hs, const int* __restrict__ rowstart,
    const int* __restrict__ deg, const ushort_t* __restrict__ esrc,
    const float* __restrict__ dinv, const float* __restrict__ bnsc,
    const float* __restrict__ bnsh, ushort_t* __restrict__ As) {
    __shared__ ushort_t sidx[2048];
    int nb0 = blockIdx.x * 16;
    int blockBeg = rowstart[nb0];
    int blockCnt = rowstart[nb0 + 15] + deg[nb0 + 15] - blockBeg;
    for (int i = threadIdx.x; i < blockCnt; i += 256) sidx[i] = esrc[blockBeg + i];
    __syncthreads();
    int l = threadIdx.x & 63;
    int q = l >> 4, cl = l & 15;
    int n = nb0 + (threadIdx.x >> 6) * 4 + q;
    const uint4* Hu4 = (const uint4*)Hs;
    int beg = rowstart[n] - blockBeg;
    int end = beg + deg[n];
    float di = dinv[n];
    uint4 h = Hu4[(size_t)n * 16 + cl];
    float a0 = lo16(h.x), a1 = hi16(h.x), a2 = lo16(h.y), a3 = hi16(h.y);
    float a4 = lo16(h.z), a5 = hi16(h.z), a6 = lo16(h.w), a7 = hi16(h.w);
    int j = beg;
    for (; j + 8 <= end; j += 8) {
        unsigned s0 = sidx[j + 0], s1 = sidx[j + 1], s2 = sidx[j + 2], s3 = sidx[j + 3];
        unsigned s4 = sidx[j + 4], s5 = sidx[j + 5], s6 = sidx[j + 6], s7 = sidx[j + 7];
        GATHER(u0, s0); GATHER(u1, s1); GATHER(u2, s2); GATHER(u3, s3);
        GATHER(u4, s4); GATHER(u5, s5); GATHER(u6, s6); GATHER(u7, s7);
        ACCUM(u0); ACCUM(u1); ACCUM(u2); ACCUM(u3);
        ACCUM(u4); ACCUM(u5); ACCUM(u6); ACCUM(u7);
    }
    for (; j + 2 <= end; j += 2) {
        unsigned s0 = sidx[j], s1 = sidx[j + 1];
        GATHER(u0, s0); GATHER(u1, s1);
        ACCUM(u0); ACCUM(u1);
    }
    if (j < end) {
        unsigned s0 = sidx[j];
        GATHER(u0, s0);
        ACCUM(u0);
    }
    int c = cl * 8;
    float4 scA = *(const float4*)&bnsc[c], scB = *(const float4*)&bnsc[c + 4];
    float4 shA = *(const float4*)&bnsh[c], shB = *(const float4*)&bnsh[c + 4];
    float o0 = fmaf(a0 * di, scA.x, shA.x);
    float o1 = fmaf(a1 * di, scA.y, shA.y);
    float o2 = fmaf(a2 * di, scA.z, shA.z);
    float o3 = fmaf(a3 * di, scA.w, shA.w);
    float o4 = fmaf(a4 * di, scB.x, shB.x);
    float o5 = fmaf(a5 * di, scB.y, shB.y);
    float o6 = fmaf(a6 * di, scB.z, shB.z);
    float o7 = fmaf(a7 * di, scB.w, shB.w);
    uint4 av;
    av.x = pack2(fmaxf(o0, 0.f) * di, fmaxf(o1, 0.f) * di);
    av.y = pack2(fmaxf(o2, 0.f) * di, fmaxf(o3, 0.f) * di);
    av.z = pack2(fmaxf(o4, 0.f) * di, fmaxf(o5, 0.f) * di);
    av.w = pack2(fmaxf(o6, 0.f) * di, fmaxf(o7, 0.f) * di);
    ((uint4*)As)[(size_t)n * 16 + cl] = av;
}

// ---------- fused GCN layer (l>=1): aggregate As -> Z (LDS) -> GEMM -> epilogue ----------
// LAST=0: output As_next = dinv*relu(BN(Z@W)).  LAST=1: output A (unscaled) + Nrm.
template<int LAST>
__global__ __launch_bounds__(512) void k_fused(
    const ushort_t* __restrict__ As, const int* __restrict__ rowstart,
    const int* __restrict__ deg, const ushort_t* __restrict__ esrc,
    const float* __restrict__ dinv, const ushort_t* __restrict__ Wb,
    const float* __restrict__ bnsc, const float* __restrict__ bnsh,
    ushort_t* __restrict__ Out, ushort_t* __restrict__ Nrm) {
    __shared__ __align__(16) ushort_t zlds[128 * 128];
    __shared__ ushort_t sidx[SCAP];
    int t = threadIdx.x;
    int nb0 = blockIdx.x * 128;
    int blockBeg = rowstart[nb0];
    int blockCnt = rowstart[nb0 + 127] + deg[nb0 + 127] - blockBeg;
    for (int i = t; i < blockCnt; i += 512) sidx[i] = esrc[blockBeg + i];
    __syncthreads();
    {
        int cl = t & 15, qd = t >> 4;   // 32 quads
        const uint4* Hu4 = (const uint4*)As;
        #pragma unroll
        for (int it = 0; it < 4; it++) {
            int nloc = it * 32 + qd;
            int n = nb0 + nloc;
            int beg = rowstart[n] - blockBeg;
            int end = beg + deg[n];
            float di = dinv[n];
            uint4 h = Hu4[(size_t)n * 16 + cl];
            float a0 = lo16(h.x), a1 = hi16(h.x), a2 = lo16(h.y), a3 = hi16(h.y);
            float a4 = lo16(h.z), a5 = hi16(h.z), a6 = lo16(h.w), a7 = hi16(h.w);
            int j = beg;
            for (; j + 8 <= end; j += 8) {
                unsigned s0 = sidx[j + 0], s1 = sidx[j + 1], s2 = sidx[j + 2], s3 = sidx[j + 3];
                unsigned s4 = sidx[j + 4], s5 = sidx[j + 5], s6 = sidx[j + 6], s7 = sidx[j + 7];
                GATHER(u0, s0); GATHER(u1, s1); GATHER(u2, s2); GATHER(u3, s3);
                GATHER(u4, s4); GATHER(u5, s5); GATHER(u6, s6); GATHER(u7, s7);
                ACCUM(u0); ACCUM(u1); ACCUM(u2); ACCUM(u3);
                ACCUM(u4); ACCUM(u5); ACCUM(u6); ACCUM(u7);
            }
            for (; j + 2 <= end; j += 2) {
                unsigned s0 = sidx[j], s1 = sidx[j + 1];
                GATHER(u0, s0); GATHER(u1, s1);
                ACCUM(u0); ACCUM(u1);
            }
            if (j < end) {
                unsigned s0 = sidx[j];
                GATHER(u0, s0);
                ACCUM(u0);
            }
            uint4 zv;
            zv.x = pack2(a0 * di, a1 * di);
            zv.y = pack2(a2 * di, a3 * di);
            zv.z = pack2(a4 * di, a5 * di);
            zv.w = pack2(a6 * di, a7 * di);
            int bcol = (cl * 16) ^ ((nloc & 7) << 4);
            *(uint4*)&zlds[nloc * DD + (bcol >> 1)] = zv;
        }
    }
    __syncthreads();
    int w = t >> 6, l = t & 63;
    int lr = l & 15, lg = l >> 4;
    int rl = w * 16 + lr;                 // this lane's Z row (A-operand)
    f32x4 acc[8];
    #pragma unroll
    for (int c = 0; c < 8; c++) acc[c] = (f32x4){0.f, 0.f, 0.f, 0.f};
    const ushort_t* wrow = Wb + (size_t)lr * DD + lg * 8;
    int swl = (rl & 7) << 4;
    for (int kt = 0; kt < 4; kt++) {
        int bcol = (kt * 64 + lg * 16) ^ swl;
        short8 a = *(const short8*)&zlds[rl * DD + (bcol >> 1)];
        #pragma unroll
        for (int c = 0; c < 8; c++) {
            short8 b = *(const short8*)(wrow + (size_t)c * 16 * DD + kt * 32);
            acc[c] = __builtin_amdgcn_mfma_f32_16x16x32_bf16(a, b, acc[c], 0, 0, 0);
        }
    }
    int rowbase = nb0 + w * 16 + lg * 4;  // rows rowbase..rowbase+3, col = c*16+lr
    if (!LAST) {
        float ds[4];
        #pragma unroll
        for (int q = 0; q < 4; q++) ds[q] = dinv[rowbase + q];
        #pragma unroll
        for (int c = 0; c < 8; c++) {
            int col = c * 16 + lr;
            float sc = bnsc[col], sh = bnsh[col];
            #pragma unroll
            for (int q = 0; q < 4; q++) {
                float v = fmaxf(fmaf(acc[c][q], sc, sh), 0.f);
                Out[(size_t)(rowbase + q) * DD + col] = f2bf(v * ds[q]);
            }
        }
    } else {
        float sq[4] = {0.f, 0.f, 0.f, 0.f};
        #pragma unroll
        for (int c = 0; c < 8; c++) {
            int col = c * 16 + lr;
            float sc = bnsc[col], sh = bnsh[col];
            #pragma unroll
            for (int q = 0; q < 4; q++) {
                float v = fmaxf(fmaf(acc[c][q], sc, sh), 0.f);
                float r = bf2f(f2bf(v));
                acc[c][q] = r;
                sq[q] += r * r;
            }
        }
        #pragma unroll
        for (int m = 1; m < 16; m <<= 1)
            #pragma unroll
            for (int q = 0; q < 4; q++) sq[q] += __shfl_xor(sq[q], m);
        float iv[4];
        #pragma unroll
        for (int q = 0; q < 4; q++) iv[q] = 1.0f / fmaxf(sqrtf(sq[q]), 1e-8f);
        #pragma unroll
        for (int c = 0; c < 8; c++) {
            int col = c * 16 + lr;
            #pragma unroll
            for (int q = 0; q < 4; q++) {
                float r = acc[c][q];
                Out[(size_t)(rowbase + q) * DD + col] = f2bf(r);
                Nrm[(size_t)(rowbase + q) * DD + col] = f2bf(r * iv[q]);
            }
        }
    }
}

// ---------- fused per-graph softmax + weighted sum ----------
__global__ __launch_bounds__(512) void k_pool2(const float* __restrict__ S,
                                               const ushort_t* __restrict__ Emb,
                                               float* __restrict__ G) {
    int b = blockIdx.x, t = threadIdx.x;
    __shared__ float red[512];
    __shared__ float w[512];
    __shared__ float red0[512], red1[512];
    float s = S[b * NPG + t];
    red[t] = s;
    __syncthreads();
    for (int o = 256; o > 0; o >>= 1) { if (t < o) red[t] = fmaxf(red[t], red[t + o]); __syncthreads(); }
    float m = red[0];
    __syncthreads();
    float e = expf(s - m);
    w[t] = e;
    red[t] = e;
    __syncthreads();
    for (int o = 256; o > 0; o >>= 1) { if (t < o) red[t] += red[t + o]; __syncthreads(); }
    float inv = 1.0f / red[0];
    int l = t & 63, ch = t >> 6;
    int nbase = b * NPG + ch * 64;
    float a0 = 0.f, a1 = 0.f;
    #pragma unroll 4
    for (int i = 0; i < 64; i++) {
        float wv = w[ch * 64 + i];
        unsigned u = ((const unsigned*)(Emb + (size_t)(nbase + i) * DD))[l];
        a0 += wv * lo16(u);
        a1 += wv * hi16(u);
    }
    red0[t] = a0; red1[t] = a1;
    __syncthreads();
    if (t < 64) {
        float s0 = 0.f, s1 = 0.f;
        #pragma unroll
        for (int c = 0; c < 8; c++) { s0 += red0[t + c * 64]; s1 += red1[t + c * 64]; }
        G[b * DD + 2 * t] = s0 * inv;
        G[b * DD + 2 * t + 1] = s1 * inv;
    }
}

// ---------- MFMA cosine-sim histogram: per-tile partials ----------
__global__ __launch_bounds__(256) void k_hist(const ushort_t* __restrict__ N1,
                                              const ushort_t* __restrict__ N2,
                                              float* __restrict__ Histp) {
    __shared__ __align__(16) ushort_t blds[128 * 128];
    __shared__ int hl[256 * 17];
    __shared__ float hred[NBINS];
    int t = threadIdx.x, w = t >> 6, l = t & 63;
    int lr = l & 15, lg = l >> 4;
    int g = blockIdx.x >> 4, ti = (blockIdx.x >> 2) & 3, tj = blockIdx.x & 3;
    {
        int r = t >> 1, h = t & 1;
        const uint4* src = (const uint4*)(N2 + ((size_t)g * NPG + tj * 128 + r) * DD + h * 64);
        #pragma unroll
        for (int i = 0; i < 8; i++) {
            int co = h * 128 + i * 16;
            int sw = co ^ ((r & 7) << 4);
            *(uint4*)&blds[r * DD + (sw >> 1)] = src[i];
        }
    }
    #pragma unroll
    for (int i = t; i < 256 * 17; i += 256) hl[i] = 0;
    if (t < NBINS) hred[t] = 0.f;
    __syncthreads();

    const ushort_t* arow = N1 + ((size_t)g * NPG + ti * 128 + w * 32 + lr) * DD + lg * 8;
    f32x4 acc[2][8];
    #pragma unroll
    for (int r = 0; r < 2; r++)
        #pragma unroll
        for (int c = 0; c < 8; c++) acc[r][c] = (f32x4){0.f, 0.f, 0.f, 0.f};
    int swl = (lr & 7) << 4;
    for (int kt = 0; kt < 4; kt++) {
        short8 a0 = *(const short8*)(arow + kt * 32);
        short8 a1 = *(const short8*)(arow + (size_t)16 * DD + kt * 32);
        int colsw = (kt * 64 + lg * 16) ^ swl;
        #pragma unroll
        for (int c = 0; c < 8; c++) {
            int row = c * 16 + lr;
            short8 b = *(const short8*)&blds[row * DD + (colsw >> 1)];
            acc[0][c] = __builtin_amdgcn_mfma_f32_16x16x32_bf16(a0, b, acc[0][c], 0, 0, 0);
            acc[1][c] = __builtin_amdgcn_mfma_f32_16x16x32_bf16(a1, b, acc[1][c], 0, 0, 0);
        }
    }
    int base = t * 17;
    #pragma unroll
    for (int r = 0; r < 2; r++)
        #pragma unroll
        for (int c = 0; c < 8; c++)
            #pragma unroll
            for (int q = 0; q < 4; q++) {
                float sim = acc[r][c][q];
                float v = floorf((sim + 1.0f) * 8.0f);
                v = fminf(fmaxf(v, 0.f), 15.f);
                atomicAdd(&hl[base + (int)v], 1);
            }
    __syncthreads();
    int bin = t & 15, r0 = (t >> 4) * 16;
    int s = 0;
    #pragma unroll
    for (int r = 0; r < 16; r++) s += hl[(r0 + r) * 17 + bin];
    atomicAdd(&hred[bin], (float)s);
    __syncthreads();
    if (t < NBINS) Histp[((size_t)g * 16 + (ti * 4 + tj)) * NBINS + t] = hred[t];
}

// ---------- NTN bilinear ----------
__global__ __launch_bounds__(128) void k_ntn(const float* __restrict__ G1,
                                             const float* __restrict__ G2,
                                             const float* __restrict__ T,
                                             const float* __restrict__ tb,
                                             float* __restrict__ TP) {
    int b = blockIdx.x, k = blockIdx.y;
    int e = threadIdx.x;
    const float* Tk = T + (size_t)k * DD * DD;
    float g2e = G2[b * DD + e];
    float acc = 0.f;
    for (int d = 0; d < DD; d++) acc += G1[b * DD + d] * Tk[(size_t)d * DD + e];
    float val = acc * g2e;
    #pragma unroll
    for (int o = 32; o > 0; o >>= 1) val += __shfl_down(val, o);
    __shared__ float ps[2];
    if ((e & 63) == 0) ps[e >> 6] = val;
    __syncthreads();
    if (e == 0) TP[b * KNTN + k] = ps[0] + ps[1] + tb[k];
}

// ---------- final MLPs: staged-LDS weights + hist partial sum ----------
__global__ __launch_bounds__(256) void k_final(const float* __restrict__ TP, const float* __restrict__ Histp,
                        const float* nw1, const float* nb1, const float* nw2, const float* nb2,
                        const float* nw3, const float* nb3,
                        const float* hw1, const float* hb1, const float* hw2, const float* hb2,
                        const float* fw1, const float* fb1, const float* fw2, const float* fb2,
                        float* __restrict__ out) {
    __shared__ float sTP[BB * 16], sHist[BB * 16];
    __shared__ float snw1[512], snw2[512], shw1[512], shw2[512];
    __shared__ float snw3[16], snb1[32], snb2[16], shb1[32], shb2[16];
    __shared__ float sfw1[136], sfb1[8], sfw2[8], sscal[2];
    int t = threadIdx.x;
    for (int i = t; i < BB * 16; i += 256) {
        sTP[i] = TP[i];
        int b = i >> 4, bin = i & 15;
        float s = 0.f;
        #pragma unroll
        for (int tile = 0; tile < 16; tile++) s += Histp[((size_t)b * 16 + tile) * NBINS + bin];
        sHist[i] = s;
    }
    for (int i = t; i < 512; i += 256) {
        snw1[i] = nw1[i]; snw2[i] = nw2[i]; shw1[i] = hw1[i]; shw2[i] = hw2[i];
    }
    if (t < 136) sfw1[t] = fw1[t];
    if (t < 32) { snb1[t] = nb1[t]; shb1[t] = hb1[t]; }
    if (t < 16) { snb2[t] = nb2[t]; shb2[t] = hb2[t]; snw3[t] = nw3[t]; }
    if (t < 8) { sfb1[t] = fb1[t]; sfw2[t] = fw2[t]; }
    if (t == 0) { sscal[0] = nb3[0]; sscal[1] = fb2[0]; }
    __syncthreads();
    if (t >= BB) return;
    int b = t;
    float h1[32];
    #pragma unroll
    for (int i = 0; i < 32; i++) {
        float a = snb1[i];
        for (int k = 0; k < 16; k++) a += sTP[b * 16 + k] * snw1[i * 16 + k];
        h1[i] = fmaxf(a, 0.f);
    }
    float h2[16];
    #pragma unroll
    for (int j = 0; j < 16; j++) {
        float a = snb2[j];
        for (int i = 0; i < 32; i++) a += h1[i] * snw2[j * 32 + i];
        h2[j] = fmaxf(a, 0.f);
    }
    float nt = sscal[0];
    for (int j = 0; j < 16; j++) nt += h2[j] * snw3[j];
    nt = 1.f / (1.f + expf(-nt));
    float hh[16]; float sum = 0.f;
    for (int k = 0; k < 16; k++) { hh[k] = sHist[b * 16 + k]; sum += hh[k]; }
    float inv = 1.f / (sum + 1e-8f);
    for (int k = 0; k < 16; k++) hh[k] *= inv;
    float g1v[32];
    #pragma unroll
    for (int i = 0; i < 32; i++) {
        float a = shb1[i];
        for (int k = 0; k < 16; k++) a += hh[k] * shw1[i * 16 + k];
        g1v[i] = fmaxf(a, 0.f);
    }
    float hemb[16];
    #pragma unroll
    for (int j = 0; j < 16; j++) {
        float a = shb2[j];
        for (int i = 0; i < 32; i++) a += g1v[i] * shw2[j * 32 + i];
        hemb[j] = a;
    }
    float comb[17];
    comb[0] = nt;
    for (int j = 0; j < 16; j++) comb[1 + j] = hemb[j];
    float f1[8];
    #pragma unroll
    for (int i = 0; i < 8; i++) {
        float a = sfb1[i];
        for (int j = 0; j < 17; j++) a += comb[j] * sfw1[i * 17 + j];
        f1[i] = fmaxf(a, 0.f);
    }
    float o = sscal[1];
    for (int i = 0; i < 8; i++) o += f1[i] * sfw2[i];
    out[b] = 1.f / (1.f + expf(-o));
}

extern "C" void kernel_launch(void* const* d_in, const int* in_sizes, int n_in,
                              void* d_out, int out_size, void* d_ws, size_t ws_size,
                              hipStream_t stream) {
    const float* x1    = (const float*)d_in[0];
    const float* x2    = (const float*)d_in[1];
    const int*   ei1   = (const int*)d_in[2];
    const int*   ei2   = (const int*)d_in[3];
    const float* gcn_w = (const float*)d_in[6];
    const float* gcn_b = (const float*)d_in[7];
    const float* bn_g  = (const float*)d_in[8];
    const float* bn_b  = (const float*)d_in[9];
    const float* bn_m  = (const float*)d_in[10];
    const float* bn_v  = (const float*)d_in[11];
    const float* ctx_w = (const float*)d_in[12];
    const float* ctx_b = (const float*)d_in[13];
    const float* att_w = (const float*)d_in[14];
    const float* att_b = (const float*)d_in[15];
    const float* ntn_T = (const float*)d_in[16];
    const float* ntn_b = (const float*)d_in[17];
    const float* nw1 = (const float*)d_in[18];
    const float* nb1 = (const float*)d_in[19];
    const float* nw2 = (const float*)d_in[20];
    const float* nb2 = (const float*)d_in[21];
    const float* nw3 = (const float*)d_in[22];
    const float* nb3 = (const float*)d_in[23];
    const float* hw1 = (const float*)d_in[24];
    const float* hb1 = (const float*)d_in[25];
    const float* hw2 = (const float*)d_in[26];
    const float* hb2 = (const float*)d_in[27];
    const float* fw1 = (const float*)d_in[28];
    const float* fb1 = (const float*)d_in[29];
    const float* fw2 = (const float*)d_in[30];
    const float* fb2 = (const float*)d_in[31];
    float* out = (float*)d_out;

    ushort_t* Xbf = (ushort_t*)d_ws;        // 2*NND (used as Nrm)
    ushort_t* Abf = Xbf + 2 * (size_t)NND;  // 2*NND
    ushort_t* Hbf = Abf + 2 * (size_t)NND;  // 2*NND
    ushort_t* wbf = Hbf + 2 * (size_t)NND;  // 4*DD*DD
    float* dinv = (float*)(wbf + 4 * DD * DD);  // 2*NN
    float* S    = dinv + 2 * NN;                // 2*NN
    float* G    = S + 2 * NN;                   // 2*BB*DD
    float* histp = G + 2 * BB * DD;             // BB*16*NBINS
    float* tp   = histp + BB * 16 * NBINS;      // BB*KNTN
    float* bnsc = tp + BB * KNTN;               // LL*DD
    float* bnsh = bnsc + LL * DD;               // LL*DD
    int* degi  = (int*)(bnsh + LL * DD);        // 2*NN
    int* rowst = degi + 2 * NN;                 // 2*NN
    int* bcnt  = rowst + 2 * NN;                // NBKT*512
    ushort_t* esrc = (ushort_t*)(bcnt + NBKT * 512);            // NBKT*BCAPE u16
    unsigned* ibuf = (unsigned*)(esrc + (size_t)NBKT * BCAPE);  // NBKT*512*BSEG u32

    k_bucket<<<577, 256, 0, stream>>>(ei1, ei2, ibuf, bcnt, gcn_w, ctx_w, wbf,
                                      gcn_b, bn_g, bn_b, bn_m, bn_v, bnsc, bnsh);
    k_bcsr<<<NBKT, 256, 0, stream>>>(ibuf, bcnt, degi, dinv, rowst, esrc);

    // layer 0 (fp32 input): GEMM then aggregate (outputs pre-scaled As_1)
    k_mgemm<0, 1><<<2 * NN / 128, 256, 0, stream>>>(nullptr, x1, x2, wbf, nullptr,
                                                    Hbf, nullptr, nullptr, nullptr, dinv);
    k_agg0<<<2 * NN / 16, 256, 0, stream>>>(Hbf, rowst, degi, esrc, dinv,
                                            bnsc, bnsh, Abf);
    // layers 1,2: fused aggregate+GEMM (linearity)
    k_fused<0><<<2 * NN / 128, 512, 0, stream>>>(Abf, rowst, degi, esrc, dinv,
                                                 wbf + (size_t)1 * DD * DD,
                                                 bnsc + 1 * DD, bnsh + 1 * DD, Hbf, nullptr);
    k_fused<1><<<2 * NN / 128, 512, 0, stream>>>(Hbf, rowst, degi, esrc, dinv,
                                                 wbf + (size_t)2 * DD * DD,
                                                 bnsc + 2 * DD, bnsh + 2 * DD, Abf, Xbf);

    k_mgemm<2, 0><<<2 * NN / 128, 256, 0, stream>>>(Abf, nullptr, nullptr,
                                                    wbf + 3 * DD * DD, ctx_b,
                                                    nullptr, att_w, att_b, S, nullptr);
    k_pool2<<<2 * BB, 512, 0, stream>>>(S, Abf, G);
    k_hist<<<BB * 16, 256, 0, stream>>>(Xbf, Xbf + NND, histp);
    k_ntn<<<dim3(BB, KNTN), 128, 0, stream>>>(G, G + BB * DD, ntn_T, ntn_b, tp);
    k_final<<<1, 256, 0, stream>>>(tp, histp, nw1, nb1, nw2, nb2, nw3, nb3,
                                   hw1, hb1, hw2, hb2, fw1, fb1, fw2, fb2, out);
}

// Round 15
// 215.821 us; speedup vs baseline: 1.0653x; 1.0653x over previous
//
#include <hip/hip_runtime.h>
#include <math.h>

#define NN 32768      // nodes per side
#define BB 64         // graphs per side
#define NPG 512
#define DD 128
#define LL 3
#define EE 524288     // edges per side
#define NBINS 16
#define KNTN 16
#define NND (NN*DD)
#define NBKT 128      // CSR buckets (512 nodes each)
#define BSEG 56       // per-(block,bucket) ibuf segment (mean 16)
#define BCAPE 10240   // esrc capacity per bucket (mean 8192, std ~90)

typedef unsigned short ushort_t;
typedef __attribute__((ext_vector_type(8))) short short8;
typedef __attribute__((ext_vector_type(4))) float f32x4;

__device__ __forceinline__ ushort_t f2bf(float f) {
    unsigned u = __builtin_bit_cast(unsigned, f);
    u += 0x7FFFu + ((u >> 16) & 1u);
    return (ushort_t)(u >> 16);
}
__device__ __forceinline__ float bf2f(ushort_t h) {
    unsigned u = ((unsigned)h) << 16;
    return __builtin_bit_cast(float, u);
}
__device__ __forceinline__ unsigned pack2(float a, float b) {
    return (unsigned)f2bf(a) | ((unsigned)f2bf(b) << 16);
}
__device__ __forceinline__ float lo16(unsigned u) { return __builtin_bit_cast(float, u << 16); }
__device__ __forceinline__ float hi16(unsigned u) { return __builtin_bit_cast(float, u & 0xffff0000u); }

// ---------- CSR pass A + prep fused ----------
__global__ __launch_bounds__(256) void k_bucket(const int* __restrict__ ei1,
                                                const int* __restrict__ ei2,
                                                unsigned* __restrict__ ibuf,
                                                int* __restrict__ bcnt,
                                                const float* __restrict__ gw,
                                                const float* __restrict__ cw,
                                                ushort_t* __restrict__ wbf,
                                                const float* __restrict__ gcn_b,
                                                const float* __restrict__ bn_g,
                                                const float* __restrict__ bn_b,
                                                const float* __restrict__ bn_m,
                                                const float* __restrict__ bn_v,
                                                float* __restrict__ bnsc,
                                                float* __restrict__ bnsh) {
    int t = threadIdx.x;
    int blk = blockIdx.x;
    if (blk >= 512) {
        if (blk < 576) {
            int i = (blk - 512) * 256 + t;
            const float4 v = (i < 3 * DD * DD / 4) ? ((const float4*)gw)[i]
                                                   : ((const float4*)cw)[i - 3 * DD * DD / 4];
            uint2 o;
            o.x = pack2(v.x, v.y);
            o.y = pack2(v.z, v.w);
            ((uint2*)wbf)[i] = o;
        } else if (t < DD) {
            #pragma unroll
            for (int l = 0; l < LL; l++) {
                int c = l * DD + t;
                float sc = bn_g[c] * rsqrtf(bn_v[c] + 1e-5f);
                bnsc[c] = sc;
                bnsh[c] = (gcn_b[c] - bn_m[c]) * sc + bn_b[c];
            }
        }
        return;
    }
    __shared__ int cnt[NBKT];
    const int* ei = (blk < 256) ? ei1 : ei2;
    int ebase = (blk & 255) * 2048;
    int addn = (blk < 256) ? 0 : NN;
    for (int i = t; i < NBKT; i += 256) cnt[i] = 0;
    __syncthreads();
    #pragma unroll
    for (int k = 0; k < 8; k++) {
        int e = ebase + t + k * 256;
        int s = ei[e] + addn;
        int d = ei[EE + e] + addn;
        unsigned p = (unsigned)s | ((unsigned)d << 16);
        int bk = (unsigned)d >> 9;
        int rk = atomicAdd(&cnt[bk], 1);
        ibuf[(size_t)(bk * 512 + blk) * BSEG + rk] = p;
    }
    __syncthreads();
    if (t < NBKT) bcnt[t * 512 + blk] = cnt[t];
}

// ---------- CSR pass B: per bucket, count -> scan -> deg/dinv/rowstart -> place ----------
__global__ __launch_bounds__(256) void k_bcsr(const unsigned* __restrict__ ibuf,
                                              const int* __restrict__ bcnt,
                                              int* __restrict__ deg,
                                              float* __restrict__ dinv,
                                              int* __restrict__ rowstart,
                                              ushort_t* __restrict__ esrc) {
    __shared__ int cnt[512];
    __shared__ int ps[256];
    __shared__ int lcur[512];
    int bk = blockIdx.x, t = threadIdx.x;
    for (int i = t; i < 512; i += 256) cnt[i] = 0;
    __syncthreads();
    for (int b = t; b < 512; b += 256) {
        int n = bcnt[bk * 512 + b];
        const unsigned* seg = ibuf + (size_t)(bk * 512 + b) * BSEG;
        for (int i = 0; i < n; i++) {
            int dl = (seg[i] >> 16) & 511;
            atomicAdd(&cnt[dl], 1);
        }
    }
    __syncthreads();
    int c0 = cnt[2 * t], c1 = cnt[2 * t + 1];
    ps[t] = c0 + c1;
    __syncthreads();
    for (int o = 1; o < 256; o <<= 1) {
        int v = (t >= o) ? ps[t - o] : 0;
        __syncthreads();
        ps[t] += v;
        __syncthreads();
    }
    int excl = (t == 0) ? 0 : ps[t - 1];
    int base = bk * BCAPE;
    int g0 = bk * 512 + 2 * t, g1 = g0 + 1;
    deg[g0] = c0; deg[g1] = c1;
    dinv[g0] = rsqrtf((float)c0 + 1.0f);
    dinv[g1] = rsqrtf((float)c1 + 1.0f);
    int r0 = base + excl, r1 = base + excl + c0;
    rowstart[g0] = r0;
    rowstart[g1] = r1;
    lcur[2 * t] = r0;
    lcur[2 * t + 1] = r1;
    __syncthreads();
    for (int b = t; b < 512; b += 256) {
        int n = bcnt[bk * 512 + b];
        const unsigned* seg = ibuf + (size_t)(bk * 512 + b) * BSEG;
        for (int i = 0; i < n; i++) {
            unsigned p = seg[i];
            int dl = (p >> 16) & 511;
            int slot = atomicAdd(&lcur[dl], 1);
            esrc[slot] = (ushort_t)(p & 0xffffu);
        }
    }
}

// ---------- MFMA GEMM: W staged in LDS (swizzled), 128 rows/block ----------
// XF=1: A-operand read from fp32 x1/x2.  EPI 0: bf16 out * dscale.
// EPI 2: bias+tanh+attention-score -> Sout.
template<int EPI, int XF>
__global__ __launch_bounds__(256) void k_mgemm(const ushort_t* __restrict__ X,
                                               const float* __restrict__ Xf1,
                                               const float* __restrict__ Xf2,
                                               const ushort_t* __restrict__ Wb,
                                               const float* __restrict__ bias,
                                               ushort_t* __restrict__ Out,
                                               const float* __restrict__ aw,
                                               const float* __restrict__ ab,
                                               float* __restrict__ Sout,
                                               const float* __restrict__ dscale) {
    __shared__ __align__(16) ushort_t wlds[128 * 128];
    int t = threadIdx.x;
    {
        int r = t >> 1, h = t & 1;
        const uint4* src = (const uint4*)(Wb + (size_t)r * DD + h * 64);
        #pragma unroll
        for (int i = 0; i < 8; i++) {
            int co = h * 128 + i * 16;
            int sw = co ^ ((r & 7) << 4);
            *(uint4*)&wlds[r * DD + (sw >> 1)] = src[i];
        }
    }
    __syncthreads();
    int w = t >> 6, l = t & 63;
    int rw = blockIdx.x * 128 + w * 32;
    int lr = l & 15, lg = l >> 4;
    f32x4 acc[2][8];
    #pragma unroll
    for (int g = 0; g < 2; g++)
        #pragma unroll
        for (int c = 0; c < 8; c++) acc[g][c] = (f32x4){0.f, 0.f, 0.f, 0.f};
    const ushort_t* xrow0 = X + (size_t)(rw + lr) * DD + lg * 8;
    const ushort_t* xrow1 = xrow0 + (size_t)16 * DD;
    const float* xf0 = nullptr;
    if (XF) {
        const float* xb = (rw < NN) ? Xf1 : (Xf2 - (size_t)NN * DD);
        xf0 = xb + (size_t)(rw + lr) * DD + lg * 8;
    }
    int swl = (lr & 7) << 4;
    for (int kt = 0; kt < 4; kt++) {
        short8 a0, a1;
        if (XF) {
            float4 va = *(const float4*)(xf0 + kt * 32);
            float4 vb = *(const float4*)(xf0 + kt * 32 + 4);
            float4 vc = *(const float4*)(xf0 + (size_t)16 * DD + kt * 32);
            float4 vd = *(const float4*)(xf0 + (size_t)16 * DD + kt * 32 + 4);
            a0[0] = (short)f2bf(va.x); a0[1] = (short)f2bf(va.y);
            a0[2] = (short)f2bf(va.z); a0[3] = (short)f2bf(va.w);
            a0[4] = (short)f2bf(vb.x); a0[5] = (short)f2bf(vb.y);
            a0[6] = (short)f2bf(vb.z); a0[7] = (short)f2bf(vb.w);
            a1[0] = (short)f2bf(vc.x); a1[1] = (short)f2bf(vc.y);
            a1[2] = (short)f2bf(vc.z); a1[3] = (short)f2bf(vc.w);
            a1[4] = (short)f2bf(vd.x); a1[5] = (short)f2bf(vd.y);
            a1[6] = (short)f2bf(vd.z); a1[7] = (short)f2bf(vd.w);
        } else {
            a0 = *(const short8*)(xrow0 + kt * 32);
            a1 = *(const short8*)(xrow1 + kt * 32);
        }
        int colsw = (kt * 64 + lg * 16) ^ swl;
        #pragma unroll
        for (int c = 0; c < 8; c++) {
            int row = c * 16 + lr;
            short8 b = *(const short8*)&wlds[row * DD + (colsw >> 1)];
            acc[0][c] = __builtin_amdgcn_mfma_f32_16x16x32_bf16(a0, b, acc[0][c], 0, 0, 0);
            acc[1][c] = __builtin_amdgcn_mfma_f32_16x16x32_bf16(a1, b, acc[1][c], 0, 0, 0);
        }
    }
    if (EPI == 0) {
        float ds[2][4];
        #pragma unroll
        for (int g = 0; g < 2; g++)
            #pragma unroll
            for (int q = 0; q < 4; q++) ds[g][q] = dscale[rw + g * 16 + lg * 4 + q];
        #pragma unroll
        for (int g = 0; g < 2; g++)
            #pragma unroll
            for (int c = 0; c < 8; c++) {
                int col = c * 16 + lr;
                #pragma unroll
                for (int q = 0; q < 4; q++)
                    Out[(size_t)(rw + g * 16 + lg * 4 + q) * DD + col] = f2bf(acc[g][c][q] * ds[g][q]);
            }
    } else {
        float rs[2][4] = {};
        #pragma unroll
        for (int c = 0; c < 8; c++) {
            int col = c * 16 + lr;
            float bv = bias[col], wv = aw[col];
            #pragma unroll
            for (int g = 0; g < 2; g++)
                #pragma unroll
                for (int q = 0; q < 4; q++)
                    rs[g][q] += tanhf(acc[g][c][q] + bv) * wv;
        }
        #pragma unroll
        for (int m = 1; m < 16; m <<= 1)
            #pragma unroll
            for (int g = 0; g < 2; g++)
                #pragma unroll
                for (int q = 0; q < 4; q++) rs[g][q] += __shfl_xor(rs[g][q], m);
        if (lr == 0) {
            float a0 = ab[0];
            #pragma unroll
            for (int g = 0; g < 2; g++)
                #pragma unroll
                for (int q = 0; q < 4; q++)
                    Sout[rw + g * 16 + lg * 4 + q] = rs[g][q] + a0;
        }
    }
}

#define GATHER(u, s) uint4 u = Hu4[(size_t)(s) * 16 + cl]
#define ACCUM(u) \
    a0 += lo16(u.x); a1 += hi16(u.x); a2 += lo16(u.y); a3 += hi16(u.y); \
    a4 += lo16(u.z); a5 += hi16(u.z); a6 += lo16(u.w); a7 += hi16(u.w)

// ---------- aggregate: quad owns a row; block's esrc range staged in LDS ----------
template<int LAST>
__global__ __launch_bounds__(256, 8) void k_agg(
    const ushort_t* __restrict__ Hs, const int* __restrict__ rowstart,
    const int* __restrict__ deg, const ushort_t* __restrict__ esrc,
    const float* __restrict__ dinv, const float* __restrict__ bnsc,
    const float* __restrict__ bnsh, ushort_t* __restrict__ A,
    ushort_t* __restrict__ Nrm) {
    __shared__ ushort_t sidx[2048];
    int nb0 = blockIdx.x * 16;             // block's 16 consecutive nodes (same bucket)
    int blockBeg = rowstart[nb0];
    int blockCnt = rowstart[nb0 + 15] + deg[nb0 + 15] - blockBeg;
    for (int i = threadIdx.x; i < blockCnt; i += 256) sidx[i] = esrc[blockBeg + i];
    __syncthreads();
    int l = threadIdx.x & 63;
    int q = l >> 4, cl = l & 15;
    int n = nb0 + (threadIdx.x >> 6) * 4 + q;
    const uint4* Hu4 = (const uint4*)Hs;
    int beg = rowstart[n] - blockBeg;      // local index into sidx
    int end = beg + deg[n];
    float di = dinv[n];
    uint4 h = Hu4[(size_t)n * 16 + cl];
    float a0 = lo16(h.x), a1 = hi16(h.x), a2 = lo16(h.y), a3 = hi16(h.y);
    float a4 = lo16(h.z), a5 = hi16(h.z), a6 = lo16(h.w), a7 = hi16(h.w);
    int j = beg;
    for (; j + 8 <= end; j += 8) {
        unsigned s0 = sidx[j + 0], s1 = sidx[j + 1], s2 = sidx[j + 2], s3 = sidx[j + 3];
        unsigned s4 = sidx[j + 4], s5 = sidx[j + 5], s6 = sidx[j + 6], s7 = sidx[j + 7];
        GATHER(u0, s0); GATHER(u1, s1); GATHER(u2, s2); GATHER(u3, s3);
        GATHER(u4, s4); GATHER(u5, s5); GATHER(u6, s6); GATHER(u7, s7);
        ACCUM(u0); ACCUM(u1); ACCUM(u2); ACCUM(u3);
        ACCUM(u4); ACCUM(u5); ACCUM(u6); ACCUM(u7);
    }
    for (; j + 2 <= end; j += 2) {
        unsigned s0 = sidx[j], s1 = sidx[j + 1];
        GATHER(u0, s0); GATHER(u1, s1);
        ACCUM(u0); ACCUM(u1);
    }
    if (j < end) {
        unsigned s0 = sidx[j];
        GATHER(u0, s0);
        ACCUM(u0);
    }
    int c = cl * 8;
    float4 scA = *(const float4*)&bnsc[c], scB = *(const float4*)&bnsc[c + 4];
    float4 shA = *(const float4*)&bnsh[c], shB = *(const float4*)&bnsh[c + 4];
    float o0 = fmaf(a0 * di, scA.x, shA.x);
    float o1 = fmaf(a1 * di, scA.y, shA.y);
    float o2 = fmaf(a2 * di, scA.z, shA.z);
    float o3 = fmaf(a3 * di, scA.w, shA.w);
    float o4 = fmaf(a4 * di, scB.x, shB.x);
    float o5 = fmaf(a5 * di, scB.y, shB.y);
    float o6 = fmaf(a6 * di, scB.z, shB.z);
    float o7 = fmaf(a7 * di, scB.w, shB.w);
    uint4 av;
    av.x = pack2(fmaxf(o0, 0.f), fmaxf(o1, 0.f));
    av.y = pack2(fmaxf(o2, 0.f), fmaxf(o3, 0.f));
    av.z = pack2(fmaxf(o4, 0.f), fmaxf(o5, 0.f));
    av.w = pack2(fmaxf(o6, 0.f), fmaxf(o7, 0.f));
    ((uint4*)A)[(size_t)n * 16 + cl] = av;
    if (LAST) {
        float r0 = lo16(av.x), r1 = hi16(av.x), r2 = lo16(av.y), r3 = hi16(av.y);
        float r4 = lo16(av.z), r5 = hi16(av.z), r6 = lo16(av.w), r7 = hi16(av.w);
        float ss = ((r0 * r0 + r1 * r1) + (r2 * r2 + r3 * r3)) +
                   ((r4 * r4 + r5 * r5) + (r6 * r6 + r7 * r7));
        #pragma unroll
        for (int o = 8; o > 0; o >>= 1) ss += __shfl_xor(ss, o);
        float inv = 1.0f / fmaxf(sqrtf(ss), 1e-8f);
        uint4 nv;
        nv.x = pack2(r0 * inv, r1 * inv);
        nv.y = pack2(r2 * inv, r3 * inv);
        nv.z = pack2(r4 * inv, r5 * inv);
        nv.w = pack2(r6 * inv, r7 * inv);
        ((uint4*)Nrm)[(size_t)n * 16 + cl] = nv;
    }
}

// ---------- fused per-graph softmax + weighted sum ----------
__global__ __launch_bounds__(512) void k_pool2(const float* __restrict__ S,
                                               const ushort_t* __restrict__ Emb,
                                               float* __restrict__ G) {
    int b = blockIdx.x, t = threadIdx.x;
    __shared__ float red[512];
    __shared__ float w[512];
    __shared__ float red0[512], red1[512];
    float s = S[b * NPG + t];
    red[t] = s;
    __syncthreads();
    for (int o = 256; o > 0; o >>= 1) { if (t < o) red[t] = fmaxf(red[t], red[t + o]); __syncthreads(); }
    float m = red[0];
    __syncthreads();
    float e = expf(s - m);
    w[t] = e;
    red[t] = e;
    __syncthreads();
    for (int o = 256; o > 0; o >>= 1) { if (t < o) red[t] += red[t + o]; __syncthreads(); }
    float inv = 1.0f / red[0];
    int l = t & 63, ch = t >> 6;
    int nbase = b * NPG + ch * 64;
    float a0 = 0.f, a1 = 0.f;
    #pragma unroll 4
    for (int i = 0; i < 64; i++) {
        float wv = w[ch * 64 + i];
        unsigned u = ((const unsigned*)(Emb + (size_t)(nbase + i) * DD))[l];
        a0 += wv * lo16(u);
        a1 += wv * hi16(u);
    }
    red0[t] = a0; red1[t] = a1;
    __syncthreads();
    if (t < 64) {
        float s0 = 0.f, s1 = 0.f;
        #pragma unroll
        for (int c = 0; c < 8; c++) { s0 += red0[t + c * 64]; s1 += red1[t + c * 64]; }
        G[b * DD + 2 * t] = s0 * inv;
        G[b * DD + 2 * t + 1] = s1 * inv;
    }
}

// ---------- MFMA cosine-sim histogram: B-tile staged in LDS; per-tile partials ----------
__global__ __launch_bounds__(256) void k_hist(const ushort_t* __restrict__ N1,
                                              const ushort_t* __restrict__ N2,
                                              float* __restrict__ Histp) {
    __shared__ __align__(16) ushort_t blds[128 * 128];
    __shared__ int hl[256 * 17];
    __shared__ float hred[NBINS];
    int t = threadIdx.x, w = t >> 6, l = t & 63;
    int lr = l & 15, lg = l >> 4;
    int g = blockIdx.x >> 4, ti = (blockIdx.x >> 2) & 3, tj = blockIdx.x & 3;
    {
        int r = t >> 1, h = t & 1;
        const uint4* src = (const uint4*)(N2 + ((size_t)g * NPG + tj * 128 + r) * DD + h * 64);
        #pragma unroll
        for (int i = 0; i < 8; i++) {
            int co = h * 128 + i * 16;
            int sw = co ^ ((r & 7) << 4);
            *(uint4*)&blds[r * DD + (sw >> 1)] = src[i];
        }
    }
    #pragma unroll
    for (int i = t; i < 256 * 17; i += 256) hl[i] = 0;
    if (t < NBINS) hred[t] = 0.f;
    __syncthreads();

    const ushort_t* arow = N1 + ((size_t)g * NPG + ti * 128 + w * 32 + lr) * DD + lg * 8;
    f32x4 acc[2][8];
    #pragma unroll
    for (int r = 0; r < 2; r++)
        #pragma unroll
        for (int c = 0; c < 8; c++) acc[r][c] = (f32x4){0.f, 0.f, 0.f, 0.f};
    int swl = (lr & 7) << 4;
    for (int kt = 0; kt < 4; kt++) {
        short8 a0 = *(const short8*)(arow + kt * 32);
        short8 a1 = *(const short8*)(arow + (size_t)16 * DD + kt * 32);
        int colsw = (kt * 64 + lg * 16) ^ swl;
        #pragma unroll
        for (int c = 0; c < 8; c++) {
            int row = c * 16 + lr;
            short8 b = *(const short8*)&blds[row * DD + (colsw >> 1)];
            acc[0][c] = __builtin_amdgcn_mfma_f32_16x16x32_bf16(a0, b, acc[0][c], 0, 0, 0);
            acc[1][c] = __builtin_amdgcn_mfma_f32_16x16x32_bf16(a1, b, acc[1][c], 0, 0, 0);
        }
    }
    int base = t * 17;
    #pragma unroll
    for (int r = 0; r < 2; r++)
        #pragma unroll
        for (int c = 0; c < 8; c++)
            #pragma unroll
            for (int q = 0; q < 4; q++) {
                float sim = acc[r][c][q];
                float v = floorf((sim + 1.0f) * 8.0f);
                v = fminf(fmaxf(v, 0.f), 15.f);
                atomicAdd(&hl[base + (int)v], 1);
            }
    __syncthreads();
    int bin = t & 15, r0 = (t >> 4) * 16;
    int s = 0;
    #pragma unroll
    for (int r = 0; r < 16; r++) s += hl[(r0 + r) * 17 + bin];
    atomicAdd(&hred[bin], (float)s);
    __syncthreads();
    if (t < NBINS) Histp[((size_t)g * 16 + (ti * 4 + tj)) * NBINS + t] = hred[t];
}

// ---------- NTN bilinear ----------
__global__ __launch_bounds__(128) void k_ntn(const float* __restrict__ G1,
                                             const float* __restrict__ G2,
                                             const float* __restrict__ T,
                                             const float* __restrict__ tb,
                                             float* __restrict__ TP) {
    int b = blockIdx.x, k = blockIdx.y;
    int e = threadIdx.x;
    const float* Tk = T + (size_t)k * DD * DD;
    float g2e = G2[b * DD + e];
    float acc = 0.f;
    for (int d = 0; d < DD; d++) acc += G1[b * DD + d] * Tk[(size_t)d * DD + e];
    float val = acc * g2e;
    #pragma unroll
    for (int o = 32; o > 0; o >>= 1) val += __shfl_down(val, o);
    __shared__ float ps[2];
    if ((e & 63) == 0) ps[e >> 6] = val;
    __syncthreads();
    if (e == 0) TP[b * KNTN + k] = ps[0] + ps[1] + tb[k];
}

// ---------- final MLPs: staged-LDS weights + hist partial sum ----------
__global__ __launch_bounds__(256) void k_final(const float* __restrict__ TP, const float* __restrict__ Histp,
                        const float* nw1, const float* nb1, const float* nw2, const float* nb2,
                        const float* nw3, const float* nb3,
                        const float* hw1, const float* hb1, const float* hw2, const float* hb2,
                        const float* fw1, const float* fb1, const float* fw2, const float* fb2,
                        float* __restrict__ out) {
    __shared__ float sTP[BB * 16], sHist[BB * 16];
    __shared__ float snw1[512], snw2[512], shw1[512], shw2[512];
    __shared__ float snw3[16], snb1[32], snb2[16], shb1[32], shb2[16];
    __shared__ float sfw1[136], sfb1[8], sfw2[8], sscal[2];
    int t = threadIdx.x;
    for (int i = t; i < BB * 16; i += 256) {
        sTP[i] = TP[i];
        int b = i >> 4, bin = i & 15;
        float s = 0.f;
        #pragma unroll
        for (int tile = 0; tile < 16; tile++) s += Histp[((size_t)b * 16 + tile) * NBINS + bin];
        sHist[i] = s;
    }
    for (int i = t; i < 512; i += 256) {
        snw1[i] = nw1[i]; snw2[i] = nw2[i]; shw1[i] = hw1[i]; shw2[i] = hw2[i];
    }
    if (t < 136) sfw1[t] = fw1[t];
    if (t < 32) { snb1[t] = nb1[t]; shb1[t] = hb1[t]; }
    if (t < 16) { snb2[t] = nb2[t]; shb2[t] = hb2[t]; snw3[t] = nw3[t]; }
    if (t < 8) { sfb1[t] = fb1[t]; sfw2[t] = fw2[t]; }
    if (t == 0) { sscal[0] = nb3[0]; sscal[1] = fb2[0]; }
    __syncthreads();
    if (t >= BB) return;
    int b = t;
    float h1[32];
    #pragma unroll
    for (int i = 0; i < 32; i++) {
        float a = snb1[i];
        for (int k = 0; k < 16; k++) a += sTP[b * 16 + k] * snw1[i * 16 + k];
        h1[i] = fmaxf(a, 0.f);
    }
    float h2[16];
    #pragma unroll
    for (int j = 0; j < 16; j++) {
        float a = snb2[j];
        for (int i = 0; i < 32; i++) a += h1[i] * snw2[j * 32 + i];
        h2[j] = fmaxf(a, 0.f);
    }
    float nt = sscal[0];
    for (int j = 0; j < 16; j++) nt += h2[j] * snw3[j];
    nt = 1.f / (1.f + expf(-nt));
    float hh[16]; float sum = 0.f;
    for (int k = 0; k < 16; k++) { hh[k] = sHist[b * 16 + k]; sum += hh[k]; }
    float inv = 1.f / (sum + 1e-8f);
    for (int k = 0; k < 16; k++) hh[k] *= inv;
    float g1v[32];
    #pragma unroll
    for (int i = 0; i < 32; i++) {
        float a = shb1[i];
        for (int k = 0; k < 16; k++) a += hh[k] * shw1[i * 16 + k];
        g1v[i] = fmaxf(a, 0.f);
    }
    float hemb[16];
    #pragma unroll
    for (int j = 0; j < 16; j++) {
        float a = shb2[j];
        for (int i = 0; i < 32; i++) a += g1v[i] * shw2[j * 32 + i];
        hemb[j] = a;
    }
    float comb[17];
    comb[0] = nt;
    for (int j = 0; j < 16; j++) comb[1 + j] = hemb[j];
    float f1[8];
    #pragma unroll
    for (int i = 0; i < 8; i++) {
        float a = sfb1[i];
        for (int j = 0; j < 17; j++) a += comb[j] * sfw1[i * 17 + j];
        f1[i] = fmaxf(a, 0.f);
    }
    float o = sscal[1];
    for (int i = 0; i < 8; i++) o += f1[i] * sfw2[i];
    out[b] = 1.f / (1.f + expf(-o));
}

extern "C" void kernel_launch(void* const* d_in, const int* in_sizes, int n_in,
                              void* d_out, int out_size, void* d_ws, size_t ws_size,
                              hipStream_t stream) {
    const float* x1    = (const float*)d_in[0];
    const float* x2    = (const float*)d_in[1];
    const int*   ei1   = (const int*)d_in[2];
    const int*   ei2   = (const int*)d_in[3];
    const float* gcn_w = (const float*)d_in[6];
    const float* gcn_b = (const float*)d_in[7];
    const float* bn_g  = (const float*)d_in[8];
    const float* bn_b  = (const float*)d_in[9];
    const float* bn_m  = (const float*)d_in[10];
    const float* bn_v  = (const float*)d_in[11];
    const float* ctx_w = (const float*)d_in[12];
    const float* ctx_b = (const float*)d_in[13];
    const float* att_w = (const float*)d_in[14];
    const float* att_b = (const float*)d_in[15];
    const float* ntn_T = (const float*)d_in[16];
    const float* ntn_b = (const float*)d_in[17];
    const float* nw1 = (const float*)d_in[18];
    const float* nb1 = (const float*)d_in[19];
    const float* nw2 = (const float*)d_in[20];
    const float* nb2 = (const float*)d_in[21];
    const float* nw3 = (const float*)d_in[22];
    const float* nb3 = (const float*)d_in[23];
    const float* hw1 = (const float*)d_in[24];
    const float* hb1 = (const float*)d_in[25];
    const float* hw2 = (const float*)d_in[26];
    const float* hb2 = (const float*)d_in[27];
    const float* fw1 = (const float*)d_in[28];
    const float* fb1 = (const float*)d_in[29];
    const float* fw2 = (const float*)d_in[30];
    const float* fb2 = (const float*)d_in[31];
    float* out = (float*)d_out;

    ushort_t* Xbf = (ushort_t*)d_ws;        // 2*NND (used as Nrm)
    ushort_t* Abf = Xbf + 2 * (size_t)NND;  // 2*NND
    ushort_t* Hbf = Abf + 2 * (size_t)NND;  // 2*NND
    ushort_t* wbf = Hbf + 2 * (size_t)NND;  // 4*DD*DD
    float* dinv = (float*)(wbf + 4 * DD * DD);  // 2*NN
    float* S    = dinv + 2 * NN;                // 2*NN
    float* G    = S + 2 * NN;                   // 2*BB*DD
    float* histp = G + 2 * BB * DD;             // BB*16*NBINS
    float* tp   = histp + BB * 16 * NBINS;      // BB*KNTN
    float* bnsc = tp + BB * KNTN;               // LL*DD
    float* bnsh = bnsc + LL * DD;               // LL*DD
    int* degi  = (int*)(bnsh + LL * DD);        // 2*NN
    int* rowst = degi + 2 * NN;                 // 2*NN
    int* bcnt  = rowst + 2 * NN;                // NBKT*512
    ushort_t* esrc = (ushort_t*)(bcnt + NBKT * 512);            // NBKT*BCAPE u16
    unsigned* ibuf = (unsigned*)(esrc + (size_t)NBKT * BCAPE);  // NBKT*512*BSEG u32

    k_bucket<<<577, 256, 0, stream>>>(ei1, ei2, ibuf, bcnt, gcn_w, ctx_w, wbf,
                                      gcn_b, bn_g, bn_b, bn_m, bn_v, bnsc, bnsh);
    k_bcsr<<<NBKT, 256, 0, stream>>>(ibuf, bcnt, degi, dinv, rowst, esrc);

    for (int l = 0; l < LL; l++) {
        if (l == 0)
            k_mgemm<0, 1><<<2 * NN / 128, 256, 0, stream>>>(nullptr, x1, x2,
                                                            wbf, nullptr, Hbf,
                                                            nullptr, nullptr, nullptr, dinv);
        else
            k_mgemm<0, 0><<<2 * NN / 128, 256, 0, stream>>>(Abf, nullptr, nullptr,
                                                            wbf + (size_t)l * DD * DD,
                                                            nullptr, Hbf, nullptr, nullptr, nullptr, dinv);
        if (l < LL - 1)
            k_agg<0><<<2 * NN / 16, 256, 0, stream>>>(Hbf, rowst, degi, esrc, dinv,
                                                      bnsc + l * DD, bnsh + l * DD, Abf, nullptr);
        else
            k_agg<1><<<2 * NN / 16, 256, 0, stream>>>(Hbf, rowst, degi, esrc, dinv,
                                                      bnsc + l * DD, bnsh + l * DD, Abf, Xbf);
    }
    k_mgemm<2, 0><<<2 * NN / 128, 256, 0, stream>>>(Abf, nullptr, nullptr,
                                                    wbf + 3 * DD * DD, ctx_b,
                                                    nullptr, att_w, att_b, S, nullptr);
    k_pool2<<<2 * BB, 512, 0, stream>>>(S, Abf, G);
    k_hist<<<BB * 16, 256, 0, stream>>>(Xbf, Xbf + NND, histp);
    k_ntn<<<dim3(BB, KNTN), 128, 0, stream>>>(G, G + BB * DD, ntn_T, ntn_b, tp);
    k_final<<<1, 256, 0, stream>>>(tp, histp, nw1, nb1, nw2, nb2, nw3, nb3,
                                   hw1, hb1, hw2, hb2, fw1, fb1, fw2, fb2, out);
}

// Round 16
// 193.957 us; speedup vs baseline: 1.1854x; 1.1127x over previous
//
#include <hip/hip_runtime.h>
#include <math.h>

#define NN 32768      // nodes per side
#define BB 64         // graphs per side
#define NPG 512
#define DD 128
#define LL 3
#define EE 524288     // edges per side
#define NBINS 16
#define KNTN 16
#define NND (NN*DD)
#define NBKT 128      // CSR buckets (512 nodes each)
#define BSEG 56       // per-(block,bucket) ibuf segment (mean 16)
#define BCAPE 10240   // esrc capacity per bucket (mean 8192, std ~90)

typedef unsigned short ushort_t;
typedef __attribute__((ext_vector_type(8))) short short8;
typedef __attribute__((ext_vector_type(4))) float f32x4;
typedef _Float16 half2_t __attribute__((ext_vector_type(2)));

__device__ __forceinline__ ushort_t f2bf(float f) {
    unsigned u = __builtin_bit_cast(unsigned, f);
    u += 0x7FFFu + ((u >> 16) & 1u);
    return (ushort_t)(u >> 16);
}
__device__ __forceinline__ float bf2f(ushort_t h) {
    unsigned u = ((unsigned)h) << 16;
    return __builtin_bit_cast(float, u);
}
__device__ __forceinline__ unsigned pack2(float a, float b) {
    return (unsigned)f2bf(a) | ((unsigned)f2bf(b) << 16);
}
__device__ __forceinline__ float lo16(unsigned u) { return __builtin_bit_cast(float, u << 16); }
__device__ __forceinline__ float hi16(unsigned u) { return __builtin_bit_cast(float, u & 0xffff0000u); }

// f32 -> fp8 e4m3 (value pre-scaled by 1/256 into f16 frame; RNE at 3-bit mantissa)
__device__ __forceinline__ unsigned char f2fp8(float v) {
    unsigned short h = __builtin_bit_cast(unsigned short, (_Float16)(v * 0.00390625f));
    h = (unsigned short)(h + 0x3F + ((h >> 7) & 1));
    return (unsigned char)(((h >> 8) & 0x80) | ((h >> 7) & 0x7f));
}

// ---------- CSR pass A + prep fused ----------
__global__ __launch_bounds__(256) void k_bucket(const int* __restrict__ ei1,
                                                const int* __restrict__ ei2,
                                                unsigned* __restrict__ ibuf,
                                                int* __restrict__ bcnt,
                                                const float* __restrict__ gw,
                                                const float* __restrict__ cw,
                                                ushort_t* __restrict__ wbf,
                                                const float* __restrict__ gcn_b,
                                                const float* __restrict__ bn_g,
                                                const float* __restrict__ bn_b,
                                                const float* __restrict__ bn_m,
                                                const float* __restrict__ bn_v,
                                                float* __restrict__ bnsc,
                                                float* __restrict__ bnsh) {
    int t = threadIdx.x;
    int blk = blockIdx.x;
    if (blk >= 512) {
        if (blk < 576) {
            int i = (blk - 512) * 256 + t;
            const float4 v = (i < 3 * DD * DD / 4) ? ((const float4*)gw)[i]
                                                   : ((const float4*)cw)[i - 3 * DD * DD / 4];
            uint2 o;
            o.x = pack2(v.x, v.y);
            o.y = pack2(v.z, v.w);
            ((uint2*)wbf)[i] = o;
        } else if (t < DD) {
            #pragma unroll
            for (int l = 0; l < LL; l++) {
                int c = l * DD + t;
                float sc = bn_g[c] * rsqrtf(bn_v[c] + 1e-5f);
                bnsc[c] = sc;
                bnsh[c] = (gcn_b[c] - bn_m[c]) * sc + bn_b[c];
            }
        }
        return;
    }
    __shared__ int cnt[NBKT];
    const int* ei = (blk < 256) ? ei1 : ei2;
    int ebase = (blk & 255) * 2048;
    int addn = (blk < 256) ? 0 : NN;
    for (int i = t; i < NBKT; i += 256) cnt[i] = 0;
    __syncthreads();
    #pragma unroll
    for (int k = 0; k < 8; k++) {
        int e = ebase + t + k * 256;
        int s = ei[e] + addn;
        int d = ei[EE + e] + addn;
        unsigned p = (unsigned)s | ((unsigned)d << 16);
        int bk = (unsigned)d >> 9;
        int rk = atomicAdd(&cnt[bk], 1);
        ibuf[(size_t)(bk * 512 + blk) * BSEG + rk] = p;
    }
    __syncthreads();
    if (t < NBKT) bcnt[t * 512 + blk] = cnt[t];
}

// ---------- CSR pass B ----------
__global__ __launch_bounds__(256) void k_bcsr(const unsigned* __restrict__ ibuf,
                                              const int* __restrict__ bcnt,
                                              int* __restrict__ deg,
                                              float* __restrict__ dinv,
                                              int* __restrict__ rowstart,
                                              ushort_t* __restrict__ esrc) {
    __shared__ int cnt[512];
    __shared__ int ps[256];
    __shared__ int lcur[512];
    int bk = blockIdx.x, t = threadIdx.x;
    for (int i = t; i < 512; i += 256) cnt[i] = 0;
    __syncthreads();
    for (int b = t; b < 512; b += 256) {
        int n = bcnt[bk * 512 + b];
        const unsigned* seg = ibuf + (size_t)(bk * 512 + b) * BSEG;
        for (int i = 0; i < n; i++) {
            int dl = (seg[i] >> 16) & 511;
            atomicAdd(&cnt[dl], 1);
        }
    }
    __syncthreads();
    int c0 = cnt[2 * t], c1 = cnt[2 * t + 1];
    ps[t] = c0 + c1;
    __syncthreads();
    for (int o = 1; o < 256; o <<= 1) {
        int v = (t >= o) ? ps[t - o] : 0;
        __syncthreads();
        ps[t] += v;
        __syncthreads();
    }
    int excl = (t == 0) ? 0 : ps[t - 1];
    int base = bk * BCAPE;
    int g0 = bk * 512 + 2 * t, g1 = g0 + 1;
    deg[g0] = c0; deg[g1] = c1;
    dinv[g0] = rsqrtf((float)c0 + 1.0f);
    dinv[g1] = rsqrtf((float)c1 + 1.0f);
    int r0 = base + excl, r1 = base + excl + c0;
    rowstart[g0] = r0;
    rowstart[g1] = r1;
    lcur[2 * t] = r0;
    lcur[2 * t + 1] = r1;
    __syncthreads();
    for (int b = t; b < 512; b += 256) {
        int n = bcnt[bk * 512 + b];
        const unsigned* seg = ibuf + (size_t)(bk * 512 + b) * BSEG;
        for (int i = 0; i < n; i++) {
            unsigned p = seg[i];
            int dl = (p >> 16) & 511;
            int slot = atomicAdd(&lcur[dl], 1);
            esrc[slot] = (ushort_t)(p & 0xffffu);
        }
    }
}

// ---------- MFMA GEMM: W staged in LDS (swizzled), 128 rows/block ----------
// XF=1: A-operand read from fp32 x1/x2.  EPI 0: fp8 out * dscale -> Out8.
// EPI 2: bias+tanh+attention-score -> Sout.
template<int EPI, int XF>
__global__ __launch_bounds__(256) void k_mgemm(const ushort_t* __restrict__ X,
                                               const float* __restrict__ Xf1,
                                               const float* __restrict__ Xf2,
                                               const ushort_t* __restrict__ Wb,
                                               const float* __restrict__ bias,
                                               unsigned char* __restrict__ Out8,
                                               const float* __restrict__ aw,
                                               const float* __restrict__ ab,
                                               float* __restrict__ Sout,
                                               const float* __restrict__ dscale) {
    __shared__ __align__(16) ushort_t wlds[128 * 128];
    int t = threadIdx.x;
    {
        int r = t >> 1, h = t & 1;
        const uint4* src = (const uint4*)(Wb + (size_t)r * DD + h * 64);
        #pragma unroll
        for (int i = 0; i < 8; i++) {
            int co = h * 128 + i * 16;
            int sw = co ^ ((r & 7) << 4);
            *(uint4*)&wlds[r * DD + (sw >> 1)] = src[i];
        }
    }
    __syncthreads();
    int w = t >> 6, l = t & 63;
    int rw = blockIdx.x * 128 + w * 32;
    int lr = l & 15, lg = l >> 4;
    f32x4 acc[2][8];
    #pragma unroll
    for (int g = 0; g < 2; g++)
        #pragma unroll
        for (int c = 0; c < 8; c++) acc[g][c] = (f32x4){0.f, 0.f, 0.f, 0.f};
    const ushort_t* xrow0 = X + (size_t)(rw + lr) * DD + lg * 8;
    const ushort_t* xrow1 = xrow0 + (size_t)16 * DD;
    const float* xf0 = nullptr;
    if (XF) {
        const float* xb = (rw < NN) ? Xf1 : (Xf2 - (size_t)NN * DD);
        xf0 = xb + (size_t)(rw + lr) * DD + lg * 8;
    }
    int swl = (lr & 7) << 4;
    for (int kt = 0; kt < 4; kt++) {
        short8 a0, a1;
        if (XF) {
            float4 va = *(const float4*)(xf0 + kt * 32);
            float4 vb = *(const float4*)(xf0 + kt * 32 + 4);
            float4 vc = *(const float4*)(xf0 + (size_t)16 * DD + kt * 32);
            float4 vd = *(const float4*)(xf0 + (size_t)16 * DD + kt * 32 + 4);
            a0[0] = (short)f2bf(va.x); a0[1] = (short)f2bf(va.y);
            a0[2] = (short)f2bf(va.z); a0[3] = (short)f2bf(va.w);
            a0[4] = (short)f2bf(vb.x); a0[5] = (short)f2bf(vb.y);
            a0[6] = (short)f2bf(vb.z); a0[7] = (short)f2bf(vb.w);
            a1[0] = (short)f2bf(vc.x); a1[1] = (short)f2bf(vc.y);
            a1[2] = (short)f2bf(vc.z); a1[3] = (short)f2bf(vc.w);
            a1[4] = (short)f2bf(vd.x); a1[5] = (short)f2bf(vd.y);
            a1[6] = (short)f2bf(vd.z); a1[7] = (short)f2bf(vd.w);
        } else {
            a0 = *(const short8*)(xrow0 + kt * 32);
            a1 = *(const short8*)(xrow1 + kt * 32);
        }
        int colsw = (kt * 64 + lg * 16) ^ swl;
        #pragma unroll
        for (int c = 0; c < 8; c++) {
            int row = c * 16 + lr;
            short8 b = *(const short8*)&wlds[row * DD + (colsw >> 1)];
            acc[0][c] = __builtin_amdgcn_mfma_f32_16x16x32_bf16(a0, b, acc[0][c], 0, 0, 0);
            acc[1][c] = __builtin_amdgcn_mfma_f32_16x16x32_bf16(a1, b, acc[1][c], 0, 0, 0);
        }
    }
    if (EPI == 0) {
        float ds[2][4];
        #pragma unroll
        for (int g = 0; g < 2; g++)
            #pragma unroll
            for (int q = 0; q < 4; q++) ds[g][q] = dscale[rw + g * 16 + lg * 4 + q];
        #pragma unroll
        for (int g = 0; g < 2; g++)
            #pragma unroll
            for (int c = 0; c < 8; c++) {
                int col = c * 16 + lr;
                #pragma unroll
                for (int q = 0; q < 4; q++)
                    Out8[(size_t)(rw + g * 16 + lg * 4 + q) * DD + col] = f2fp8(acc[g][c][q] * ds[g][q]);
            }
    } else {
        float rs[2][4] = {};
        #pragma unroll
        for (int c = 0; c < 8; c++) {
            int col = c * 16 + lr;
            float bv = bias[col], wv = aw[col];
            #pragma unroll
            for (int g = 0; g < 2; g++)
                #pragma unroll
                for (int q = 0; q < 4; q++)
                    rs[g][q] += tanhf(acc[g][c][q] + bv) * wv;
        }
        #pragma unroll
        for (int m = 1; m < 16; m <<= 1)
            #pragma unroll
            for (int g = 0; g < 2; g++)
                #pragma unroll
                for (int q = 0; q < 4; q++) rs[g][q] += __shfl_xor(rs[g][q], m);
        if (lr == 0) {
            float a0 = ab[0];
            #pragma unroll
            for (int g = 0; g < 2; g++)
                #pragma unroll
                for (int q = 0; q < 4; q++)
                    Sout[rw + g * 16 + lg * 4 + q] = rs[g][q] + a0;
        }
    }
}

// fp8x4 pairwise decode into f16-frame packed accumulators (true value = frame * 256)
#define DEC8(u, A, B) { \
    unsigned pa = (u) & 0x00ff00ffu; \
    unsigned pb = ((u) >> 8) & 0x00ff00ffu; \
    pa += pa & 0x00800080u; \
    pb += pb & 0x00800080u; \
    A += __builtin_bit_cast(half2_t, (pa << 7) & 0xff80ff80u); \
    B += __builtin_bit_cast(half2_t, (pb << 7) & 0xff80ff80u); }

#define GATHER8(u, s) uint2 u = H8u[(size_t)(s) * 16 + cl]
#define ACC8(u) DEC8(u.x, A0, B0); DEC8(u.y, A1, B1)

// ---------- aggregate: quad owns a row; fp8 H gathers (128B/row); LDS-staged indices ----------
template<int LAST>
__global__ __launch_bounds__(256, 8) void k_agg(
    const unsigned char* __restrict__ H8, const int* __restrict__ rowstart,
    const int* __restrict__ deg, const ushort_t* __restrict__ esrc,
    const float* __restrict__ dinv, const float* __restrict__ bnsc,
    const float* __restrict__ bnsh, ushort_t* __restrict__ A,
    ushort_t* __restrict__ Nrm) {
    __shared__ ushort_t sidx[2048];
    int nb0 = blockIdx.x * 16;             // block's 16 consecutive nodes (same bucket)
    int blockBeg = rowstart[nb0];
    int blockCnt = rowstart[nb0 + 15] + deg[nb0 + 15] - blockBeg;
    for (int i = threadIdx.x; i < blockCnt; i += 256) sidx[i] = esrc[blockBeg + i];
    __syncthreads();
    int l = threadIdx.x & 63;
    int q = l >> 4, cl = l & 15;
    int n = nb0 + (threadIdx.x >> 6) * 4 + q;
    const uint2* H8u = (const uint2*)H8;
    int beg = rowstart[n] - blockBeg;      // local index into sidx
    int end = beg + deg[n];
    float di = dinv[n];
    half2_t A0 = (half2_t)0, B0 = (half2_t)0, A1 = (half2_t)0, B1 = (half2_t)0;
    {
        uint2 h = H8u[(size_t)n * 16 + cl];
        ACC8(h);
    }
    int j = beg;
    for (; j + 8 <= end; j += 8) {
        unsigned s0 = sidx[j + 0], s1 = sidx[j + 1], s2 = sidx[j + 2], s3 = sidx[j + 3];
        unsigned s4 = sidx[j + 4], s5 = sidx[j + 5], s6 = sidx[j + 6], s7 = sidx[j + 7];
        GATHER8(u0, s0); GATHER8(u1, s1); GATHER8(u2, s2); GATHER8(u3, s3);
        GATHER8(u4, s4); GATHER8(u5, s5); GATHER8(u6, s6); GATHER8(u7, s7);
        ACC8(u0); ACC8(u1); ACC8(u2); ACC8(u3);
        ACC8(u4); ACC8(u5); ACC8(u6); ACC8(u7);
    }
    for (; j + 2 <= end; j += 2) {
        unsigned s0 = sidx[j], s1 = sidx[j + 1];
        GATHER8(u0, s0); GATHER8(u1, s1);
        ACC8(u0); ACC8(u1);
    }
    if (j < end) {
        unsigned s0 = sidx[j];
        GATHER8(u0, s0);
        ACC8(u0);
    }
    // unpack: A0=(f0,f2) B0=(f1,f3) A1=(f4,f6) B1=(f5,f7); true value = frame*256
    float a0 = (float)A0.x, a2 = (float)A0.y, a1 = (float)B0.x, a3 = (float)B0.y;
    float a4 = (float)A1.x, a6 = (float)A1.y, a5 = (float)B1.x, a7 = (float)B1.y;
    float di2 = di * 256.0f;
    int c = cl * 8;
    float4 scA = *(const float4*)&bnsc[c], scB = *(const float4*)&bnsc[c + 4];
    float4 shA = *(const float4*)&bnsh[c], shB = *(const float4*)&bnsh[c + 4];
    float o0 = fmaf(a0 * di2, scA.x, shA.x);
    float o1 = fmaf(a1 * di2, scA.y, shA.y);
    float o2 = fmaf(a2 * di2, scA.z, shA.z);
    float o3 = fmaf(a3 * di2, scA.w, shA.w);
    float o4 = fmaf(a4 * di2, scB.x, shB.x);
    float o5 = fmaf(a5 * di2, scB.y, shB.y);
    float o6 = fmaf(a6 * di2, scB.z, shB.z);
    float o7 = fmaf(a7 * di2, scB.w, shB.w);
    uint4 av;
    av.x = pack2(fmaxf(o0, 0.f), fmaxf(o1, 0.f));
    av.y = pack2(fmaxf(o2, 0.f), fmaxf(o3, 0.f));
    av.z = pack2(fmaxf(o4, 0.f), fmaxf(o5, 0.f));
    av.w = pack2(fmaxf(o6, 0.f), fmaxf(o7, 0.f));
    ((uint4*)A)[(size_t)n * 16 + cl] = av;
    if (LAST) {
        float r0 = lo16(av.x), r1 = hi16(av.x), r2 = lo16(av.y), r3 = hi16(av.y);
        float r4 = lo16(av.z), r5 = hi16(av.z), r6 = lo16(av.w), r7 = hi16(av.w);
        float ss = ((r0 * r0 + r1 * r1) + (r2 * r2 + r3 * r3)) +
                   ((r4 * r4 + r5 * r5) + (r6 * r6 + r7 * r7));
        #pragma unroll
        for (int o = 8; o > 0; o >>= 1) ss += __shfl_xor(ss, o);
        float inv = 1.0f / fmaxf(sqrtf(ss), 1e-8f);
        uint4 nv;
        nv.x = pack2(r0 * inv, r1 * inv);
        nv.y = pack2(r2 * inv, r3 * inv);
        nv.z = pack2(r4 * inv, r5 * inv);
        nv.w = pack2(r6 * inv, r7 * inv);
        ((uint4*)Nrm)[(size_t)n * 16 + cl] = nv;
    }
}

// ---------- fused per-graph softmax + weighted sum ----------
__global__ __launch_bounds__(512) void k_pool2(const float* __restrict__ S,
                                               const ushort_t* __restrict__ Emb,
                                               float* __restrict__ G) {
    int b = blockIdx.x, t = threadIdx.x;
    __shared__ float red[512];
    __shared__ float w[512];
    __shared__ float red0[512], red1[512];
    float s = S[b * NPG + t];
    red[t] = s;
    __syncthreads();
    for (int o = 256; o > 0; o >>= 1) { if (t < o) red[t] = fmaxf(red[t], red[t + o]); __syncthreads(); }
    float m = red[0];
    __syncthreads();
    float e = expf(s - m);
    w[t] = e;
    red[t] = e;
    __syncthreads();
    for (int o = 256; o > 0; o >>= 1) { if (t < o) red[t] += red[t + o]; __syncthreads(); }
    float inv = 1.0f / red[0];
    int l = t & 63, ch = t >> 6;
    int nbase = b * NPG + ch * 64;
    float a0 = 0.f, a1 = 0.f;
    #pragma unroll 4
    for (int i = 0; i < 64; i++) {
        float wv = w[ch * 64 + i];
        unsigned u = ((const unsigned*)(Emb + (size_t)(nbase + i) * DD))[l];
        a0 += wv * lo16(u);
        a1 += wv * hi16(u);
    }
    red0[t] = a0; red1[t] = a1;
    __syncthreads();
    if (t < 64) {
        float s0 = 0.f, s1 = 0.f;
        #pragma unroll
        for (int c = 0; c < 8; c++) { s0 += red0[t + c * 64]; s1 += red1[t + c * 64]; }
        G[b * DD + 2 * t] = s0 * inv;
        G[b * DD + 2 * t + 1] = s1 * inv;
    }
}

// ---------- MFMA cosine-sim histogram: B-tile staged in LDS; per-tile partials ----------
__global__ __launch_bounds__(256) void k_hist(const ushort_t* __restrict__ N1,
                                              const ushort_t* __restrict__ N2,
                                              float* __restrict__ Histp) {
    __shared__ __align__(16) ushort_t blds[128 * 128];
    __shared__ int hl[256 * 17];
    __shared__ float hred[NBINS];
    int t = threadIdx.x, w = t >> 6, l = t & 63;
    int lr = l & 15, lg = l >> 4;
    int g = blockIdx.x >> 4, ti = (blockIdx.x >> 2) & 3, tj = blockIdx.x & 3;
    {
        int r = t >> 1, h = t & 1;
        const uint4* src = (const uint4*)(N2 + ((size_t)g * NPG + tj * 128 + r) * DD + h * 64);
        #pragma unroll
        for (int i = 0; i < 8; i++) {
            int co = h * 128 + i * 16;
            int sw = co ^ ((r & 7) << 4);
            *(uint4*)&blds[r * DD + (sw >> 1)] = src[i];
        }
    }
    #pragma unroll
    for (int i = t; i < 256 * 17; i += 256) hl[i] = 0;
    if (t < NBINS) hred[t] = 0.f;
    __syncthreads();

    const ushort_t* arow = N1 + ((size_t)g * NPG + ti * 128 + w * 32 + lr) * DD + lg * 8;
    f32x4 acc[2][8];
    #pragma unroll
    for (int r = 0; r < 2; r++)
        #pragma unroll
        for (int c = 0; c < 8; c++) acc[r][c] = (f32x4){0.f, 0.f, 0.f, 0.f};
    int swl = (lr & 7) << 4;
    for (int kt = 0; kt < 4; kt++) {
        short8 a0 = *(const short8*)(arow + kt * 32);
        short8 a1 = *(const short8*)(arow + (size_t)16 * DD + kt * 32);
        int colsw = (kt * 64 + lg * 16) ^ swl;
        #pragma unroll
        for (int c = 0; c < 8; c++) {
            int row = c * 16 + lr;
            short8 b = *(const short8*)&blds[row * DD + (colsw >> 1)];
            acc[0][c] = __builtin_amdgcn_mfma_f32_16x16x32_bf16(a0, b, acc[0][c], 0, 0, 0);
            acc[1][c] = __builtin_amdgcn_mfma_f32_16x16x32_bf16(a1, b, acc[1][c], 0, 0, 0);
        }
    }
    int base = t * 17;
    #pragma unroll
    for (int r = 0; r < 2; r++)
        #pragma unroll
        for (int c = 0; c < 8; c++)
            #pragma unroll
            for (int q = 0; q < 4; q++) {
                float sim = acc[r][c][q];
                float v = floorf((sim + 1.0f) * 8.0f);
                v = fminf(fmaxf(v, 0.f), 15.f);
                atomicAdd(&hl[base + (int)v], 1);
            }
    __syncthreads();
    int bin = t & 15, r0 = (t >> 4) * 16;
    int s = 0;
    #pragma unroll
    for (int r = 0; r < 16; r++) s += hl[(r0 + r) * 17 + bin];
    atomicAdd(&hred[bin], (float)s);
    __syncthreads();
    if (t < NBINS) Histp[((size_t)g * 16 + (ti * 4 + tj)) * NBINS + t] = hred[t];
}

// ---------- NTN bilinear ----------
__global__ __launch_bounds__(128) void k_ntn(const float* __restrict__ G1,
                                             const float* __restrict__ G2,
                                             const float* __restrict__ T,
                                             const float* __restrict__ tb,
                                             float* __restrict__ TP) {
    int b = blockIdx.x, k = blockIdx.y;
    int e = threadIdx.x;
    const float* Tk = T + (size_t)k * DD * DD;
    float g2e = G2[b * DD + e];
    float acc = 0.f;
    for (int d = 0; d < DD; d++) acc += G1[b * DD + d] * Tk[(size_t)d * DD + e];
    float val = acc * g2e;
    #pragma unroll
    for (int o = 32; o > 0; o >>= 1) val += __shfl_down(val, o);
    __shared__ float ps[2];
    if ((e & 63) == 0) ps[e >> 6] = val;
    __syncthreads();
    if (e == 0) TP[b * KNTN + k] = ps[0] + ps[1] + tb[k];
}

// ---------- final MLPs: staged-LDS weights + hist partial sum ----------
__global__ __launch_bounds__(256) void k_final(const float* __restrict__ TP, const float* __restrict__ Histp,
                        const float* nw1, const float* nb1, const float* nw2, const float* nb2,
                        const float* nw3, const float* nb3,
                        const float* hw1, const float* hb1, const float* hw2, const float* hb2,
                        const float* fw1, const float* fb1, const float* fw2, const float* fb2,
                        float* __restrict__ out) {
    __shared__ float sTP[BB * 16], sHist[BB * 16];
    __shared__ float snw1[512], snw2[512], shw1[512], shw2[512];
    __shared__ float snw3[16], snb1[32], snb2[16], shb1[32], shb2[16];
    __shared__ float sfw1[136], sfb1[8], sfw2[8], sscal[2];
    int t = threadIdx.x;
    for (int i = t; i < BB * 16; i += 256) {
        sTP[i] = TP[i];
        int b = i >> 4, bin = i & 15;
        float s = 0.f;
        #pragma unroll
        for (int tile = 0; tile < 16; tile++) s += Histp[((size_t)b * 16 + tile) * NBINS + bin];
        sHist[i] = s;
    }
    for (int i = t; i < 512; i += 256) {
        snw1[i] = nw1[i]; snw2[i] = nw2[i]; shw1[i] = hw1[i]; shw2[i] = hw2[i];
    }
    if (t < 136) sfw1[t] = fw1[t];
    if (t < 32) { snb1[t] = nb1[t]; shb1[t] = hb1[t]; }
    if (t < 16) { snb2[t] = nb2[t]; shb2[t] = hb2[t]; snw3[t] = nw3[t]; }
    if (t < 8) { sfb1[t] = fb1[t]; sfw2[t] = fw2[t]; }
    if (t == 0) { sscal[0] = nb3[0]; sscal[1] = fb2[0]; }
    __syncthreads();
    if (t >= BB) return;
    int b = t;
    float h1[32];
    #pragma unroll
    for (int i = 0; i < 32; i++) {
        float a = snb1[i];
        for (int k = 0; k < 16; k++) a += sTP[b * 16 + k] * snw1[i * 16 + k];
        h1[i] = fmaxf(a, 0.f);
    }
    float h2[16];
    #pragma unroll
    for (int j = 0; j < 16; j++) {
        float a = snb2[j];
        for (int i = 0; i < 32; i++) a += h1[i] * snw2[j * 32 + i];
        h2[j] = fmaxf(a, 0.f);
    }
    float nt = sscal[0];
    for (int j = 0; j < 16; j++) nt += h2[j] * snw3[j];
    nt = 1.f / (1.f + expf(-nt));
    float hh[16]; float sum = 0.f;
    for (int k = 0; k < 16; k++) { hh[k] = sHist[b * 16 + k]; sum += hh[k]; }
    float inv = 1.f / (sum + 1e-8f);
    for (int k = 0; k < 16; k++) hh[k] *= inv;
    float g1v[32];
    #pragma unroll
    for (int i = 0; i < 32; i++) {
        float a = shb1[i];
        for (int k = 0; k < 16; k++) a += hh[k] * shw1[i * 16 + k];
        g1v[i] = fmaxf(a, 0.f);
    }
    float hemb[16];
    #pragma unroll
    for (int j = 0; j < 16; j++) {
        float a = shb2[j];
        for (int i = 0; i < 32; i++) a += g1v[i] * shw2[j * 32 + i];
        hemb[j] = a;
    }
    float comb[17];
    comb[0] = nt;
    for (int j = 0; j < 16; j++) comb[1 + j] = hemb[j];
    float f1[8];
    #pragma unroll
    for (int i = 0; i < 8; i++) {
        float a = sfb1[i];
        for (int j = 0; j < 17; j++) a += comb[j] * sfw1[i * 17 + j];
        f1[i] = fmaxf(a, 0.f);
    }
    float o = sscal[1];
    for (int i = 0; i < 8; i++) o += f1[i] * sfw2[i];
    out[b] = 1.f / (1.f + expf(-o));
}

extern "C" void kernel_launch(void* const* d_in, const int* in_sizes, int n_in,
                              void* d_out, int out_size, void* d_ws, size_t ws_size,
                              hipStream_t stream) {
    const float* x1    = (const float*)d_in[0];
    const float* x2    = (const float*)d_in[1];
    const int*   ei1   = (const int*)d_in[2];
    const int*   ei2   = (const int*)d_in[3];
    const float* gcn_w = (const float*)d_in[6];
    const float* gcn_b = (const float*)d_in[7];
    const float* bn_g  = (const float*)d_in[8];
    const float* bn_b  = (const float*)d_in[9];
    const float* bn_m  = (const float*)d_in[10];
    const float* bn_v  = (const float*)d_in[11];
    const float* ctx_w = (const float*)d_in[12];
    const float* ctx_b = (const float*)d_in[13];
    const float* att_w = (const float*)d_in[14];
    const float* att_b = (const float*)d_in[15];
    const float* ntn_T = (const float*)d_in[16];
    const float* ntn_b = (const float*)d_in[17];
    const float* nw1 = (const float*)d_in[18];
    const float* nb1 = (const float*)d_in[19];
    const float* nw2 = (const float*)d_in[20];
    const float* nb2 = (const float*)d_in[21];
    const float* nw3 = (const float*)d_in[22];
    const float* nb3 = (const float*)d_in[23];
    const float* hw1 = (const float*)d_in[24];
    const float* hb1 = (const float*)d_in[25];
    const float* hw2 = (const float*)d_in[26];
    const float* hb2 = (const float*)d_in[27];
    const float* fw1 = (const float*)d_in[28];
    const float* fb1 = (const float*)d_in[29];
    const float* fw2 = (const float*)d_in[30];
    const float* fb2 = (const float*)d_in[31];
    float* out = (float*)d_out;

    ushort_t* Xbf = (ushort_t*)d_ws;        // 2*NND (used as Nrm)
    ushort_t* Abf = Xbf + 2 * (size_t)NND;  // 2*NND
    unsigned char* H8 = (unsigned char*)(Abf + 2 * (size_t)NND);  // 2*NND bytes (fp8)
    ushort_t* wbf = (ushort_t*)(H8 + 2 * (size_t)NND);            // 4*DD*DD
    float* dinv = (float*)(wbf + 4 * DD * DD);  // 2*NN
    float* S    = dinv + 2 * NN;                // 2*NN
    float* G    = S + 2 * NN;                   // 2*BB*DD
    float* histp = G + 2 * BB * DD;             // BB*16*NBINS
    float* tp   = histp + BB * 16 * NBINS;      // BB*KNTN
    float* bnsc = tp + BB * KNTN;               // LL*DD
    float* bnsh = bnsc + LL * DD;               // LL*DD
    int* degi  = (int*)(bnsh + LL * DD);        // 2*NN
    int* rowst = degi + 2 * NN;                 // 2*NN
    int* bcnt  = rowst + 2 * NN;                // NBKT*512
    ushort_t* esrc = (ushort_t*)(bcnt + NBKT * 512);            // NBKT*BCAPE u16
    unsigned* ibuf = (unsigned*)(esrc + (size_t)NBKT * BCAPE);  // NBKT*512*BSEG u32

    k_bucket<<<577, 256, 0, stream>>>(ei1, ei2, ibuf, bcnt, gcn_w, ctx_w, wbf,
                                      gcn_b, bn_g, bn_b, bn_m, bn_v, bnsc, bnsh);
    k_bcsr<<<NBKT, 256, 0, stream>>>(ibuf, bcnt, degi, dinv, rowst, esrc);

    for (int l = 0; l < LL; l++) {
        if (l == 0)
            k_mgemm<0, 1><<<2 * NN / 128, 256, 0, stream>>>(nullptr, x1, x2,
                                                            wbf, nullptr, H8,
                                                            nullptr, nullptr, nullptr, dinv);
        else
            k_mgemm<0, 0><<<2 * NN / 128, 256, 0, stream>>>(Abf, nullptr, nullptr,
                                                            wbf + (size_t)l * DD * DD,
                                                            nullptr, H8, nullptr, nullptr, nullptr, dinv);
        if (l < LL - 1)
            k_agg<0><<<2 * NN / 16, 256, 0, stream>>>(H8, rowst, degi, esrc, dinv,
                                                      bnsc + l * DD, bnsh + l * DD, Abf, nullptr);
        else
            k_agg<1><<<2 * NN / 16, 256, 0, stream>>>(H8, rowst, degi, esrc, dinv,
                                                      bnsc + l * DD, bnsh + l * DD, Abf, Xbf);
    }
    k_mgemm<2, 0><<<2 * NN / 128, 256, 0, stream>>>(Abf, nullptr, nullptr,
                                                    wbf + 3 * DD * DD, ctx_b,
                                                    nullptr, att_w, att_b, S, nullptr);
    k_pool2<<<2 * BB, 512, 0, stream>>>(S, Abf, G);
    k_hist<<<BB * 16, 256, 0, stream>>>(Xbf, Xbf + NND, histp);
    k_ntn<<<dim3(BB, KNTN), 128, 0, stream>>>(G, G + BB * DD, ntn_T, ntn_b, tp);
    k_final<<<1, 256, 0, stream>>>(tp, histp, nw1, nb1, nw2, nb2, nw3, nb3,
                                   hw1, hb1, hw2, hb2, fw1, fb1, fw2, fb2, out);
}

// Round 17
// 191.108 us; speedup vs baseline: 1.2031x; 1.0149x over previous
//
#include <hip/hip_runtime.h>
#include <math.h>

#define NN 32768      // nodes per side
#define BB 64         // graphs per side
#define NPG 512
#define DD 128
#define LL 3
#define EE 524288     // edges per side
#define NBINS 16
#define KNTN 16
#define NND (NN*DD)
#define NBKT 128      // CSR buckets (512 nodes each)
#define BSEG 56       // per-(block,bucket) ibuf segment (mean 16)
#define BCAPE 10240   // esrc capacity per bucket (mean 8192, std ~90)

typedef unsigned short ushort_t;
typedef __attribute__((ext_vector_type(8))) short short8;
typedef __attribute__((ext_vector_type(4))) float f32x4;
typedef _Float16 half2_t __attribute__((ext_vector_type(2)));

__device__ __forceinline__ ushort_t f2bf(float f) {
    unsigned u = __builtin_bit_cast(unsigned, f);
    u += 0x7FFFu + ((u >> 16) & 1u);
    return (ushort_t)(u >> 16);
}
__device__ __forceinline__ float bf2f(ushort_t h) {
    unsigned u = ((unsigned)h) << 16;
    return __builtin_bit_cast(float, u);
}
__device__ __forceinline__ unsigned pack2(float a, float b) {
    return (unsigned)f2bf(a) | ((unsigned)f2bf(b) << 16);
}
__device__ __forceinline__ float lo16(unsigned u) { return __builtin_bit_cast(float, u << 16); }
__device__ __forceinline__ float hi16(unsigned u) { return __builtin_bit_cast(float, u & 0xffff0000u); }

// f32 -> fp8 e4m3 (value pre-scaled by 1/256 into f16 frame; RNE at 3-bit mantissa)
__device__ __forceinline__ unsigned char f2fp8(float v) {
    unsigned short h = __builtin_bit_cast(unsigned short, (_Float16)(v * 0.00390625f));
    h = (unsigned short)(h + 0x3F + ((h >> 7) & 1));
    return (unsigned char)(((h >> 8) & 0x80) | ((h >> 7) & 0x7f));
}

// ---------- CSR pass A + prep fused (LDS-staged coalesced segment writes) ----------
__global__ __launch_bounds__(256) void k_bucket(const int* __restrict__ ei1,
                                                const int* __restrict__ ei2,
                                                unsigned* __restrict__ ibuf,
                                                int* __restrict__ bcnt,
                                                const float* __restrict__ gw,
                                                const float* __restrict__ cw,
                                                ushort_t* __restrict__ wbf,
                                                const float* __restrict__ gcn_b,
                                                const float* __restrict__ bn_g,
                                                const float* __restrict__ bn_b,
                                                const float* __restrict__ bn_m,
                                                const float* __restrict__ bn_v,
                                                float* __restrict__ bnsc,
                                                float* __restrict__ bnsh) {
    int t = threadIdx.x;
    int blk = blockIdx.x;
    if (blk >= 512) {
        if (blk < 576) {
            int i = (blk - 512) * 256 + t;
            const float4 v = (i < 3 * DD * DD / 4) ? ((const float4*)gw)[i]
                                                   : ((const float4*)cw)[i - 3 * DD * DD / 4];
            uint2 o;
            o.x = pack2(v.x, v.y);
            o.y = pack2(v.z, v.w);
            ((uint2*)wbf)[i] = o;
        } else if (t < DD) {
            #pragma unroll
            for (int l = 0; l < LL; l++) {
                int c = l * DD + t;
                float sc = bn_g[c] * rsqrtf(bn_v[c] + 1e-5f);
                bnsc[c] = sc;
                bnsh[c] = (gcn_b[c] - bn_m[c]) * sc + bn_b[c];
            }
        }
        return;
    }
    __shared__ int cnt[NBKT], off[NBKT];
    __shared__ unsigned stage[2048];
    const int* ei = (blk < 256) ? ei1 : ei2;
    int ebase = (blk & 255) * 2048;
    int addn = (blk < 256) ? 0 : NN;
    for (int i = t; i < NBKT; i += 256) cnt[i] = 0;
    __syncthreads();
    unsigned pk[8]; int rk[8];
    #pragma unroll
    for (int k = 0; k < 8; k++) {
        int e = ebase + t + k * 256;
        int s = ei[e] + addn;
        int d = ei[EE + e] + addn;
        pk[k] = (unsigned)s | ((unsigned)d << 16);
    }
    #pragma unroll
    for (int k = 0; k < 8; k++) {
        int bk = pk[k] >> 25;
        rk[k] = atomicAdd(&cnt[bk], 1);
    }
    __syncthreads();
    if (t < NBKT) off[t] = cnt[t];
    __syncthreads();
    for (int o = 1; o < NBKT; o <<= 1) {
        int v = 0;
        if (t < NBKT && t >= o) v = off[t - o];
        __syncthreads();
        if (t < NBKT) off[t] += v;
        __syncthreads();
    }
    #pragma unroll
    for (int k = 0; k < 8; k++) {
        int bk = pk[k] >> 25;
        stage[off[bk] - cnt[bk] + rk[k]] = pk[k];
    }
    __syncthreads();
    #pragma unroll
    for (int k = 0; k < 8; k++) {
        int idx = t + k * 256;
        unsigned p = stage[idx];
        int bk = p >> 25;
        int pos = idx - (off[bk] - cnt[bk]);
        ibuf[(size_t)(bk * 512 + blk) * BSEG + pos] = p;
    }
    if (t < NBKT) bcnt[t * 512 + blk] = cnt[t];
}

// ---------- CSR pass B ----------
__global__ __launch_bounds__(256) void k_bcsr(const unsigned* __restrict__ ibuf,
                                              const int* __restrict__ bcnt,
                                              int* __restrict__ deg,
                                              float* __restrict__ dinv,
                                              int* __restrict__ rowstart,
                                              ushort_t* __restrict__ esrc) {
    __shared__ int cnt[512];
    __shared__ int ps[256];
    __shared__ int lcur[512];
    int bk = blockIdx.x, t = threadIdx.x;
    for (int i = t; i < 512; i += 256) cnt[i] = 0;
    __syncthreads();
    for (int b = t; b < 512; b += 256) {
        int n = bcnt[bk * 512 + b];
        const unsigned* seg = ibuf + (size_t)(bk * 512 + b) * BSEG;
        for (int i = 0; i < n; i++) {
            int dl = (seg[i] >> 16) & 511;
            atomicAdd(&cnt[dl], 1);
        }
    }
    __syncthreads();
    int c0 = cnt[2 * t], c1 = cnt[2 * t + 1];
    ps[t] = c0 + c1;
    __syncthreads();
    for (int o = 1; o < 256; o <<= 1) {
        int v = (t >= o) ? ps[t - o] : 0;
        __syncthreads();
        ps[t] += v;
        __syncthreads();
    }
    int excl = (t == 0) ? 0 : ps[t - 1];
    int base = bk * BCAPE;
    int g0 = bk * 512 + 2 * t, g1 = g0 + 1;
    deg[g0] = c0; deg[g1] = c1;
    dinv[g0] = rsqrtf((float)c0 + 1.0f);
    dinv[g1] = rsqrtf((float)c1 + 1.0f);
    int r0 = base + excl, r1 = base + excl + c0;
    rowstart[g0] = r0;
    rowstart[g1] = r1;
    lcur[2 * t] = r0;
    lcur[2 * t + 1] = r1;
    __syncthreads();
    for (int b = t; b < 512; b += 256) {
        int n = bcnt[bk * 512 + b];
        const unsigned* seg = ibuf + (size_t)(bk * 512 + b) * BSEG;
        for (int i = 0; i < n; i++) {
            unsigned p = seg[i];
            int dl = (p >> 16) & 511;
            int slot = atomicAdd(&lcur[dl], 1);
            esrc[slot] = (ushort_t)(p & 0xffffu);
        }
    }
}

// ---------- MFMA GEMM: W staged in LDS (swizzled), 128 rows/block ----------
// XF=1: A-operand read from fp32 x1/x2.  EPI 0: fp8 out * dscale -> Out8.
// EPI 2: bias+tanh+attention-score -> Sout.
template<int EPI, int XF>
__global__ __launch_bounds__(256) void k_mgemm(const ushort_t* __restrict__ X,
                                               const float* __restrict__ Xf1,
                                               const float* __restrict__ Xf2,
                                               const ushort_t* __restrict__ Wb,
                                               const float* __restrict__ bias,
                                               unsigned char* __restrict__ Out8,
                                               const float* __restrict__ aw,
                                               const float* __restrict__ ab,
                                               float* __restrict__ Sout,
                                               const float* __restrict__ dscale) {
    __shared__ __align__(16) ushort_t wlds[128 * 128];
    int t = threadIdx.x;
    {
        int r = t >> 1, h = t & 1;
        const uint4* src = (const uint4*)(Wb + (size_t)r * DD + h * 64);
        #pragma unroll
        for (int i = 0; i < 8; i++) {
            int co = h * 128 + i * 16;
            int sw = co ^ ((r & 7) << 4);
            *(uint4*)&wlds[r * DD + (sw >> 1)] = src[i];
        }
    }
    __syncthreads();
    int w = t >> 6, l = t & 63;
    int rw = blockIdx.x * 128 + w * 32;
    int lr = l & 15, lg = l >> 4;
    f32x4 acc[2][8];
    #pragma unroll
    for (int g = 0; g < 2; g++)
        #pragma unroll
        for (int c = 0; c < 8; c++) acc[g][c] = (f32x4){0.f, 0.f, 0.f, 0.f};
    const ushort_t* xrow0 = X + (size_t)(rw + lr) * DD + lg * 8;
    const ushort_t* xrow1 = xrow0 + (size_t)16 * DD;
    const float* xf0 = nullptr;
    if (XF) {
        const float* xb = (rw < NN) ? Xf1 : (Xf2 - (size_t)NN * DD);
        xf0 = xb + (size_t)(rw + lr) * DD + lg * 8;
    }
    int swl = (lr & 7) << 4;
    for (int kt = 0; kt < 4; kt++) {
        short8 a0, a1;
        if (XF) {
            float4 va = *(const float4*)(xf0 + kt * 32);
            float4 vb = *(const float4*)(xf0 + kt * 32 + 4);
            float4 vc = *(const float4*)(xf0 + (size_t)16 * DD + kt * 32);
            float4 vd = *(const float4*)(xf0 + (size_t)16 * DD + kt * 32 + 4);
            a0[0] = (short)f2bf(va.x); a0[1] = (short)f2bf(va.y);
            a0[2] = (short)f2bf(va.z); a0[3] = (short)f2bf(va.w);
            a0[4] = (short)f2bf(vb.x); a0[5] = (short)f2bf(vb.y);
            a0[6] = (short)f2bf(vb.z); a0[7] = (short)f2bf(vb.w);
            a1[0] = (short)f2bf(vc.x); a1[1] = (short)f2bf(vc.y);
            a1[2] = (short)f2bf(vc.z); a1[3] = (short)f2bf(vc.w);
            a1[4] = (short)f2bf(vd.x); a1[5] = (short)f2bf(vd.y);
            a1[6] = (short)f2bf(vd.z); a1[7] = (short)f2bf(vd.w);
        } else {
            a0 = *(const short8*)(xrow0 + kt * 32);
            a1 = *(const short8*)(xrow1 + kt * 32);
        }
        int colsw = (kt * 64 + lg * 16) ^ swl;
        #pragma unroll
        for (int c = 0; c < 8; c++) {
            int row = c * 16 + lr;
            short8 b = *(const short8*)&wlds[row * DD + (colsw >> 1)];
            acc[0][c] = __builtin_amdgcn_mfma_f32_16x16x32_bf16(a0, b, acc[0][c], 0, 0, 0);
            acc[1][c] = __builtin_amdgcn_mfma_f32_16x16x32_bf16(a1, b, acc[1][c], 0, 0, 0);
        }
    }
    if (EPI == 0) {
        float ds[2][4];
        #pragma unroll
        for (int g = 0; g < 2; g++)
            #pragma unroll
            for (int q = 0; q < 4; q++) ds[g][q] = dscale[rw + g * 16 + lg * 4 + q];
        #pragma unroll
        for (int g = 0; g < 2; g++)
            #pragma unroll
            for (int c = 0; c < 8; c++) {
                int col = c * 16 + lr;
                #pragma unroll
                for (int q = 0; q < 4; q++)
                    Out8[(size_t)(rw + g * 16 + lg * 4 + q) * DD + col] = f2fp8(acc[g][c][q] * ds[g][q]);
            }
    } else {
        float rs[2][4] = {};
        #pragma unroll
        for (int c = 0; c < 8; c++) {
            int col = c * 16 + lr;
            float bv = bias[col], wv = aw[col];
            #pragma unroll
            for (int g = 0; g < 2; g++)
                #pragma unroll
                for (int q = 0; q < 4; q++)
                    rs[g][q] += tanhf(acc[g][c][q] + bv) * wv;
        }
        #pragma unroll
        for (int m = 1; m < 16; m <<= 1)
            #pragma unroll
            for (int g = 0; g < 2; g++)
                #pragma unroll
                for (int q = 0; q < 4; q++) rs[g][q] += __shfl_xor(rs[g][q], m);
        if (lr == 0) {
            float a0 = ab[0];
            #pragma unroll
            for (int g = 0; g < 2; g++)
                #pragma unroll
                for (int q = 0; q < 4; q++)
                    Sout[rw + g * 16 + lg * 4 + q] = rs[g][q] + a0;
        }
    }
}

// fp8x4 pairwise decode into f16-frame packed accumulators (true value = frame * 256)
#define DEC8(u, A, B) { \
    unsigned pa = (u) & 0x00ff00ffu; \
    unsigned pb = ((u) >> 8) & 0x00ff00ffu; \
    pa += pa & 0x00800080u; \
    pb += pb & 0x00800080u; \
    A += __builtin_bit_cast(half2_t, (pa << 7) & 0xff80ff80u); \
    B += __builtin_bit_cast(half2_t, (pb << 7) & 0xff80ff80u); }

#define GATHER8(u, s) uint2 u = H8u[(size_t)(s) * 16 + cl]
#define ACC8(u) DEC8(u.x, A0, B0); DEC8(u.y, A1, B1)

// ---------- aggregate: quad owns a row; fp8 H gathers (128B/row); LDS-staged indices ----------
template<int LAST>
__global__ __launch_bounds__(256, 8) void k_agg(
    const unsigned char* __restrict__ H8, const int* __restrict__ rowstart,
    const int* __restrict__ deg, const ushort_t* __restrict__ esrc,
    const float* __restrict__ dinv, const float* __restrict__ bnsc,
    const float* __restrict__ bnsh, ushort_t* __restrict__ A,
    ushort_t* __restrict__ Nrm) {
    __shared__ ushort_t sidx[2048];
    int nb0 = blockIdx.x * 16;             // block's 16 consecutive nodes (same bucket)
    int blockBeg = rowstart[nb0];
    int blockCnt = rowstart[nb0 + 15] + deg[nb0 + 15] - blockBeg;
    for (int i = threadIdx.x; i < blockCnt; i += 256) sidx[i] = esrc[blockBeg + i];
    __syncthreads();
    int l = threadIdx.x & 63;
    int q = l >> 4, cl = l & 15;
    int n = nb0 + (threadIdx.x >> 6) * 4 + q;
    const uint2* H8u = (const uint2*)H8;
    int beg = rowstart[n] - blockBeg;      // local index into sidx
    int end = beg + deg[n];
    float di = dinv[n];
    half2_t A0 = (half2_t)0, B0 = (half2_t)0, A1 = (half2_t)0, B1 = (half2_t)0;
    {
        uint2 h = H8u[(size_t)n * 16 + cl];
        ACC8(h);
    }
    int j = beg;
    for (; j + 8 <= end; j += 8) {
        unsigned s0 = sidx[j + 0], s1 = sidx[j + 1], s2 = sidx[j + 2], s3 = sidx[j + 3];
        unsigned s4 = sidx[j + 4], s5 = sidx[j + 5], s6 = sidx[j + 6], s7 = sidx[j + 7];
        GATHER8(u0, s0); GATHER8(u1, s1); GATHER8(u2, s2); GATHER8(u3, s3);
        GATHER8(u4, s4); GATHER8(u5, s5); GATHER8(u6, s6); GATHER8(u7, s7);
        ACC8(u0); ACC8(u1); ACC8(u2); ACC8(u3);
        ACC8(u4); ACC8(u5); ACC8(u6); ACC8(u7);
    }
    for (; j + 2 <= end; j += 2) {
        unsigned s0 = sidx[j], s1 = sidx[j + 1];
        GATHER8(u0, s0); GATHER8(u1, s1);
        ACC8(u0); ACC8(u1);
    }
    if (j < end) {
        unsigned s0 = sidx[j];
        GATHER8(u0, s0);
        ACC8(u0);
    }
    // unpack: A0=(f0,f2) B0=(f1,f3) A1=(f4,f6) B1=(f5,f7); true value = frame*256
    float a0 = (float)A0.x, a2 = (float)A0.y, a1 = (float)B0.x, a3 = (float)B0.y;
    float a4 = (float)A1.x, a6 = (float)A1.y, a5 = (float)B1.x, a7 = (float)B1.y;
    float di2 = di * 256.0f;
    int c = cl * 8;
    float4 scA = *(const float4*)&bnsc[c], scB = *(const float4*)&bnsc[c + 4];
    float4 shA = *(const float4*)&bnsh[c], shB = *(const float4*)&bnsh[c + 4];
    float o0 = fmaf(a0 * di2, scA.x, shA.x);
    float o1 = fmaf(a1 * di2, scA.y, shA.y);
    float o2 = fmaf(a2 * di2, scA.z, shA.z);
    float o3 = fmaf(a3 * di2, scA.w, shA.w);
    float o4 = fmaf(a4 * di2, scB.x, shB.x);
    float o5 = fmaf(a5 * di2, scB.y, shB.y);
    float o6 = fmaf(a6 * di2, scB.z, shB.z);
    float o7 = fmaf(a7 * di2, scB.w, shB.w);
    uint4 av;
    av.x = pack2(fmaxf(o0, 0.f), fmaxf(o1, 0.f));
    av.y = pack2(fmaxf(o2, 0.f), fmaxf(o3, 0.f));
    av.z = pack2(fmaxf(o4, 0.f), fmaxf(o5, 0.f));
    av.w = pack2(fmaxf(o6, 0.f), fmaxf(o7, 0.f));
    ((uint4*)A)[(size_t)n * 16 + cl] = av;
    if (LAST) {
        float r0 = lo16(av.x), r1 = hi16(av.x), r2 = lo16(av.y), r3 = hi16(av.y);
        float r4 = lo16(av.z), r5 = hi16(av.z), r6 = lo16(av.w), r7 = hi16(av.w);
        float ss = ((r0 * r0 + r1 * r1) + (r2 * r2 + r3 * r3)) +
                   ((r4 * r4 + r5 * r5) + (r6 * r6 + r7 * r7));
        #pragma unroll
        for (int o = 8; o > 0; o >>= 1) ss += __shfl_xor(ss, o);
        float inv = 1.0f / fmaxf(sqrtf(ss), 1e-8f);
        uint4 nv;
        nv.x = pack2(r0 * inv, r1 * inv);
        nv.y = pack2(r2 * inv, r3 * inv);
        nv.z = pack2(r4 * inv, r5 * inv);
        nv.w = pack2(r6 * inv, r7 * inv);
        ((uint4*)Nrm)[(size_t)n * 16 + cl] = nv;
    }
}

// ---------- fused per-graph softmax + weighted sum ----------
__global__ __launch_bounds__(512) void k_pool2(const float* __restrict__ S,
                                               const ushort_t* __restrict__ Emb,
                                               float* __restrict__ G) {
    int b = blockIdx.x, t = threadIdx.x;
    __shared__ float red[512];
    __shared__ float w[512];
    __shared__ float red0[512], red1[512];
    float s = S[b * NPG + t];
    red[t] = s;
    __syncthreads();
    for (int o = 256; o > 0; o >>= 1) { if (t < o) red[t] = fmaxf(red[t], red[t + o]); __syncthreads(); }
    float m = red[0];
    __syncthreads();
    float e = expf(s - m);
    w[t] = e;
    red[t] = e;
    __syncthreads();
    for (int o = 256; o > 0; o >>= 1) { if (t < o) red[t] += red[t + o]; __syncthreads(); }
    float inv = 1.0f / red[0];
    int l = t & 63, ch = t >> 6;
    int nbase = b * NPG + ch * 64;
    float a0 = 0.f, a1 = 0.f;
    #pragma unroll 4
    for (int i = 0; i < 64; i++) {
        float wv = w[ch * 64 + i];
        unsigned u = ((const unsigned*)(Emb + (size_t)(nbase + i) * DD))[l];
        a0 += wv * lo16(u);
        a1 += wv * hi16(u);
    }
    red0[t] = a0; red1[t] = a1;
    __syncthreads();
    if (t < 64) {
        float s0 = 0.f, s1 = 0.f;
        #pragma unroll
        for (int c = 0; c < 8; c++) { s0 += red0[t + c * 64]; s1 += red1[t + c * 64]; }
        G[b * DD + 2 * t] = s0 * inv;
        G[b * DD + 2 * t + 1] = s1 * inv;
    }
}

// ---------- MFMA cosine-sim histogram: B-tile staged in LDS; per-tile partials ----------
__global__ __launch_bounds__(256) void k_hist(const ushort_t* __restrict__ N1,
                                              const ushort_t* __restrict__ N2,
                                              float* __restrict__ Histp) {
    __shared__ __align__(16) ushort_t blds[128 * 128];
    __shared__ int hl[256 * 17];
    __shared__ float hred[NBINS];
    int t = threadIdx.x, w = t >> 6, l = t & 63;
    int lr = l & 15, lg = l >> 4;
    int g = blockIdx.x >> 4, ti = (blockIdx.x >> 2) & 3, tj = blockIdx.x & 3;
    {
        int r = t >> 1, h = t & 1;
        const uint4* src = (const uint4*)(N2 + ((size_t)g * NPG + tj * 128 + r) * DD + h * 64);
        #pragma unroll
        for (int i = 0; i < 8; i++) {
            int co = h * 128 + i * 16;
            int sw = co ^ ((r & 7) << 4);
            *(uint4*)&blds[r * DD + (sw >> 1)] = src[i];
        }
    }
    #pragma unroll
    for (int i = t; i < 256 * 17; i += 256) hl[i] = 0;
    if (t < NBINS) hred[t] = 0.f;
    __syncthreads();

    const ushort_t* arow = N1 + ((size_t)g * NPG + ti * 128 + w * 32 + lr) * DD + lg * 8;
    f32x4 acc[2][8];
    #pragma unroll
    for (int r = 0; r < 2; r++)
        #pragma unroll
        for (int c = 0; c < 8; c++) acc[r][c] = (f32x4){0.f, 0.f, 0.f, 0.f};
    int swl = (lr & 7) << 4;
    for (int kt = 0; kt < 4; kt++) {
        short8 a0 = *(const short8*)(arow + kt * 32);
        short8 a1 = *(const short8*)(arow + (size_t)16 * DD + kt * 32);
        int colsw = (kt * 64 + lg * 16) ^ swl;
        #pragma unroll
        for (int c = 0; c < 8; c++) {
            int row = c * 16 + lr;
            short8 b = *(const short8*)&blds[row * DD + (colsw >> 1)];
            acc[0][c] = __builtin_amdgcn_mfma_f32_16x16x32_bf16(a0, b, acc[0][c], 0, 0, 0);
            acc[1][c] = __builtin_amdgcn_mfma_f32_16x16x32_bf16(a1, b, acc[1][c], 0, 0, 0);
        }
    }
    int base = t * 17;
    #pragma unroll
    for (int r = 0; r < 2; r++)
        #pragma unroll
        for (int c = 0; c < 8; c++)
            #pragma unroll
            for (int q = 0; q < 4; q++) {
                float sim = acc[r][c][q];
                float v = floorf((sim + 1.0f) * 8.0f);
                v = fminf(fmaxf(v, 0.f), 15.f);
                atomicAdd(&hl[base + (int)v], 1);
            }
    __syncthreads();
    int bin = t & 15, r0 = (t >> 4) * 16;
    int s = 0;
    #pragma unroll
    for (int r = 0; r < 16; r++) s += hl[(r0 + r) * 17 + bin];
    atomicAdd(&hred[bin], (float)s);
    __syncthreads();
    if (t < NBINS) Histp[((size_t)g * 16 + (ti * 4 + tj)) * NBINS + t] = hred[t];
}

// ---------- NTN bilinear ----------
__global__ __launch_bounds__(128) void k_ntn(const float* __restrict__ G1,
                                             const float* __restrict__ G2,
                                             const float* __restrict__ T,
                                             const float* __restrict__ tb,
                                             float* __restrict__ TP) {
    int b = blockIdx.x, k = blockIdx.y;
    int e = threadIdx.x;
    const float* Tk = T + (size_t)k * DD * DD;
    float g2e = G2[b * DD + e];
    float acc = 0.f;
    for (int d = 0; d < DD; d++) acc += G1[b * DD + d] * Tk[(size_t)d * DD + e];
    float val = acc * g2e;
    #pragma unroll
    for (int o = 32; o > 0; o >>= 1) val += __shfl_down(val, o);
    __shared__ float ps[2];
    if ((e & 63) == 0) ps[e >> 6] = val;
    __syncthreads();
    if (e == 0) TP[b * KNTN + k] = ps[0] + ps[1] + tb[k];
}

// ---------- final MLPs: staged-LDS weights + hist partial sum ----------
__global__ __launch_bounds__(256) void k_final(const float* __restrict__ TP, const float* __restrict__ Histp,
                        const float* nw1, const float* nb1, const float* nw2, const float* nb2,
                        const float* nw3, const float* nb3,
                        const float* hw1, const float* hb1, const float* hw2, const float* hb2,
                        const float* fw1, const float* fb1, const float* fw2, const float* fb2,
                        float* __restrict__ out) {
    __shared__ float sTP[BB * 16], sHist[BB * 16];
    __shared__ float snw1[512], snw2[512], shw1[512], shw2[512];
    __shared__ float snw3[16], snb1[32], snb2[16], shb1[32], shb2[16];
    __shared__ float sfw1[136], sfb1[8], sfw2[8], sscal[2];
    int t = threadIdx.x;
    for (int i = t; i < BB * 16; i += 256) {
        sTP[i] = TP[i];
        int b = i >> 4, bin = i & 15;
        float s = 0.f;
        #pragma unroll
        for (int tile = 0; tile < 16; tile++) s += Histp[((size_t)b * 16 + tile) * NBINS + bin];
        sHist[i] = s;
    }
    for (int i = t; i < 512; i += 256) {
        snw1[i] = nw1[i]; snw2[i] = nw2[i]; shw1[i] = hw1[i]; shw2[i] = hw2[i];
    }
    if (t < 136) sfw1[t] = fw1[t];
    if (t < 32) { snb1[t] = nb1[t]; shb1[t] = hb1[t]; }
    if (t < 16) { snb2[t] = nb2[t]; shb2[t] = hb2[t]; snw3[t] = nw3[t]; }
    if (t < 8) { sfb1[t] = fb1[t]; sfw2[t] = fw2[t]; }
    if (t == 0) { sscal[0] = nb3[0]; sscal[1] = fb2[0]; }
    __syncthreads();
    if (t >= BB) return;
    int b = t;
    float h1[32];
    #pragma unroll
    for (int i = 0; i < 32; i++) {
        float a = snb1[i];
        for (int k = 0; k < 16; k++) a += sTP[b * 16 + k] * snw1[i * 16 + k];
        h1[i] = fmaxf(a, 0.f);
    }
    float h2[16];
    #pragma unroll
    for (int j = 0; j < 16; j++) {
        float a = snb2[j];
        for (int i = 0; i < 32; i++) a += h1[i] * snw2[j * 32 + i];
        h2[j] = fmaxf(a, 0.f);
    }
    float nt = sscal[0];
    for (int j = 0; j < 16; j++) nt += h2[j] * snw3[j];
    nt = 1.f / (1.f + expf(-nt));
    float hh[16]; float sum = 0.f;
    for (int k = 0; k < 16; k++) { hh[k] = sHist[b * 16 + k]; sum += hh[k]; }
    float inv = 1.f / (sum + 1e-8f);
    for (int k = 0; k < 16; k++) hh[k] *= inv;
    float g1v[32];
    #pragma unroll
    for (int i = 0; i < 32; i++) {
        float a = shb1[i];
        for (int k = 0; k < 16; k++) a += hh[k] * shw1[i * 16 + k];
        g1v[i] = fmaxf(a, 0.f);
    }
    float hemb[16];
    #pragma unroll
    for (int j = 0; j < 16; j++) {
        float a = shb2[j];
        for (int i = 0; i < 32; i++) a += g1v[i] * shw2[j * 32 + i];
        hemb[j] = a;
    }
    float comb[17];
    comb[0] = nt;
    for (int j = 0; j < 16; j++) comb[1 + j] = hemb[j];
    float f1[8];
    #pragma unroll
    for (int i = 0; i < 8; i++) {
        float a = sfb1[i];
        for (int j = 0; j < 17; j++) a += comb[j] * sfw1[i * 17 + j];
        f1[i] = fmaxf(a, 0.f);
    }
    float o = sscal[1];
    for (int i = 0; i < 8; i++) o += f1[i] * sfw2[i];
    out[b] = 1.f / (1.f + expf(-o));
}

extern "C" void kernel_launch(void* const* d_in, const int* in_sizes, int n_in,
                              void* d_out, int out_size, void* d_ws, size_t ws_size,
                              hipStream_t stream) {
    const float* x1    = (const float*)d_in[0];
    const float* x2    = (const float*)d_in[1];
    const int*   ei1   = (const int*)d_in[2];
    const int*   ei2   = (const int*)d_in[3];
    const float* gcn_w = (const float*)d_in[6];
    const float* gcn_b = (const float*)d_in[7];
    const float* bn_g  = (const float*)d_in[8];
    const float* bn_b  = (const float*)d_in[9];
    const float* bn_m  = (const float*)d_in[10];
    const float* bn_v  = (const float*)d_in[11];
    const float* ctx_w = (const float*)d_in[12];
    const float* ctx_b = (const float*)d_in[13];
    const float* att_w = (const float*)d_in[14];
    const float* att_b = (const float*)d_in[15];
    const float* ntn_T = (const float*)d_in[16];
    const float* ntn_b = (const float*)d_in[17];
    const float* nw1 = (const float*)d_in[18];
    const float* nb1 = (const float*)d_in[19];
    const float* nw2 = (const float*)d_in[20];
    const float* nb2 = (const float*)d_in[21];
    const float* nw3 = (const float*)d_in[22];
    const float* nb3 = (const float*)d_in[23];
    const float* hw1 = (const float*)d_in[24];
    const float* hb1 = (const float*)d_in[25];
    const float* hw2 = (const float*)d_in[26];
    const float* hb2 = (const float*)d_in[27];
    const float* fw1 = (const float*)d_in[28];
    const float* fb1 = (const float*)d_in[29];
    const float* fw2 = (const float*)d_in[30];
    const float* fb2 = (const float*)d_in[31];
    float* out = (float*)d_out;

    ushort_t* Xbf = (ushort_t*)d_ws;        // 2*NND (used as Nrm)
    ushort_t* Abf = Xbf + 2 * (size_t)NND;  // 2*NND
    unsigned char* H8 = (unsigned char*)(Abf + 2 * (size_t)NND);  // 2*NND bytes (fp8)
    ushort_t* wbf = (ushort_t*)(H8 + 2 * (size_t)NND);            // 4*DD*DD
    float* dinv = (float*)(wbf + 4 * DD * DD);  // 2*NN
    float* S    = dinv + 2 * NN;                // 2*NN
    float* G    = S + 2 * NN;                   // 2*BB*DD
    float* histp = G + 2 * BB * DD;             // BB*16*NBINS
    float* tp   = histp + BB * 16 * NBINS;      // BB*KNTN
    float* bnsc = tp + BB * KNTN;               // LL*DD
    float* bnsh = bnsc + LL * DD;               // LL*DD
    int* degi  = (int*)(bnsh + LL * DD);        // 2*NN
    int* rowst = degi + 2 * NN;                 // 2*NN
    int* bcnt  = rowst + 2 * NN;                // NBKT*512
    ushort_t* esrc = (ushort_t*)(bcnt + NBKT * 512);            // NBKT*BCAPE u16
    unsigned* ibuf = (unsigned*)(esrc + (size_t)NBKT * BCAPE);  // NBKT*512*BSEG u32

    k_bucket<<<577, 256, 0, stream>>>(ei1, ei2, ibuf, bcnt, gcn_w, ctx_w, wbf,
                                      gcn_b, bn_g, bn_b, bn_m, bn_v, bnsc, bnsh);
    k_bcsr<<<NBKT, 256, 0, stream>>>(ibuf, bcnt, degi, dinv, rowst, esrc);

    for (int l = 0; l < LL; l++) {
        if (l == 0)
            k_mgemm<0, 1><<<2 * NN / 128, 256, 0, stream>>>(nullptr, x1, x2,
                                                            wbf, nullptr, H8,
                                                            nullptr, nullptr, nullptr, dinv);
        else
            k_mgemm<0, 0><<<2 * NN / 128, 256, 0, stream>>>(Abf, nullptr, nullptr,
                                                            wbf + (size_t)l * DD * DD,
                                                            nullptr, H8, nullptr, nullptr, nullptr, dinv);
        if (l < LL - 1)
            k_agg<0><<<2 * NN / 16, 256, 0, stream>>>(H8, rowst, degi, esrc, dinv,
                                                      bnsc + l * DD, bnsh + l * DD, Abf, nullptr);
        else
            k_agg<1><<<2 * NN / 16, 256, 0, stream>>>(H8, rowst, degi, esrc, dinv,
                                                      bnsc + l * DD, bnsh + l * DD, Abf, Xbf);
    }
    k_mgemm<2, 0><<<2 * NN / 128, 256, 0, stream>>>(Abf, nullptr, nullptr,
                                                    wbf + 3 * DD * DD, ctx_b,
                                                    nullptr, att_w, att_b, S, nullptr);
    k_pool2<<<2 * BB, 512, 0, stream>>>(S, Abf, G);
    k_hist<<<BB * 16, 256, 0, stream>>>(Xbf, Xbf + NND, histp);
    k_ntn<<<dim3(BB, KNTN), 128, 0, stream>>>(G, G + BB * DD, ntn_T, ntn_b, tp);
    k_final<<<1, 256, 0, stream>>>(tp, histp, nw1, nb1, nw2, nb2, nw3, nb3,
                                   hw1, hb1, hw2, hb2, fw1, fb1, fw2, fb2, out);
}